// Round 1
// baseline (3447.599 us; speedup 1.0000x reference)
//
#include <hip/hip_runtime.h>
#include <cstdint>
#include <cstddef>

// ---- model dims ----
#define B_    1024
#define L_    50
#define EMB_  63
#define CD_   60
#define SEQC_ 243
#define H_    100
#define G4_   400     // 4*H
#define DH_   200     // 2*H
#define NHID_ 128
#define KD_   10000   // L_*DH_

// ---------- helpers ----------
__device__ __forceinline__ float sigf(float x){ return 1.f/(1.f+expf(-x)); }
__device__ __forceinline__ unsigned short f2bf(float f){
  unsigned int x = __float_as_uint(f);
  unsigned int r = x + 0x7fffu + ((x>>16)&1u);   // RNE
  return (unsigned short)(r>>16);
}
__device__ __forceinline__ float bf2f(unsigned short u){
  return __uint_as_float(((unsigned int)u)<<16);
}

// =====================================================================
// K1: embedding lookup + 3 conv branches (k=2,3,8) + ReLU + maxpool(5,p1)
//     + right-pad to L, concatenated into seq (B, L, 243)
// one block per batch element
// =====================================================================
template<int KH>
__device__ __forceinline__ void conv_branch(
    const float (&x0s)[EMB_][64], float (&ys)[CD_][49],
    const float* __restrict__ w, const float* __restrict__ cb,
    float* __restrict__ seq, int b, int co, int tid)
{
  const int Lc = 51 - KH;        // valid-conv length
  const int Lp = Lc - 2;         // after maxpool(5, stride1, pad1)
  const int nt8 = (Lc + 7) >> 3;
  // compute conv + bias + relu into ys
  for (int task = tid; task < CD_*nt8; task += 256) {
    int o = task / nt8, tc = (task % nt8) << 3;
    float acc[8];
    float bb = cb[o];
    #pragma unroll
    for (int j = 0; j < 8; ++j) acc[j] = bb;
    for (int c = 0; c < EMB_; ++c) {
      float xw[16];
      const float* xr = &x0s[c][tc];            // tc <= 48, reads pad zeros beyond l=49
      *(float4*)&xw[0]  = *(const float4*)&xr[0];
      *(float4*)&xw[4]  = *(const float4*)&xr[4];
      *(float4*)&xw[8]  = *(const float4*)&xr[8];
      *(float4*)&xw[12] = *(const float4*)&xr[12];
      const float* wr = &w[(o*EMB_ + c)*KH];
      float wv[KH];
      #pragma unroll
      for (int tau = 0; tau < KH; ++tau) wv[tau] = wr[tau];
      #pragma unroll
      for (int tau = 0; tau < KH; ++tau) {
        #pragma unroll
        for (int j = 0; j < 8; ++j) acc[j] = fmaf(xw[tau+j], wv[tau], acc[j]);
      }
    }
    #pragma unroll
    for (int j = 0; j < 8; ++j) {
      int t = tc + j;
      if (t < Lc) ys[o][t] = fmaxf(acc[j], 0.f);
    }
  }
  __syncthreads();
  // maxpool + zero-pad + write to seq channels [co, co+60)
  for (int idx = tid; idx < L_*CD_; idx += 256) {
    int l = idx / CD_, o = idx - (idx/CD_)*CD_;
    float vm = 0.f;                              // relu output >= 0
    if (l < Lp) {
      int lo = (l-1 < 0) ? 0 : l-1;
      int hi = (l+3 >= Lc) ? Lc-1 : l+3;
      for (int t = lo; t <= hi; ++t) vm = fmaxf(vm, ys[o][t]);
    }
    seq[((size_t)b*L_ + l)*SEQC_ + co + o] = vm;
  }
  __syncthreads();
}

__global__ __launch_bounds__(256) void k_embconv(
    const int* __restrict__ x, const float* __restrict__ emb1, const float* __restrict__ emb2,
    const float* __restrict__ cw2, const float* __restrict__ cb2,
    const float* __restrict__ cw3, const float* __restrict__ cb3,
    const float* __restrict__ cw8, const float* __restrict__ cb8,
    float* __restrict__ seq)
{
  __shared__ float x0s[EMB_][64];   // padded to 64 (zeros beyond l=49)
  __shared__ float ys[CD_][49];
  __shared__ int   xs[L_];
  const int b = blockIdx.x, tid = threadIdx.x;
  if (tid < L_) xs[tid] = x[b*L_ + tid];
  __syncthreads();
  for (int idx = tid; idx < EMB_*64; idx += 256) {
    int c = idx >> 6, l = idx & 63;
    float v = 0.f;
    if (l < L_) { int e = xs[l]; v = (c < 21) ? emb1[e*21 + c] : emb2[e*42 + (c-21)]; }
    x0s[c][l] = v;
  }
  __syncthreads();
  // x0 part of seq (channels [0,63))
  for (int idx = tid; idx < L_*EMB_; idx += 256) {
    int l = idx / EMB_, c = idx - (idx/EMB_)*EMB_;
    seq[((size_t)b*L_ + l)*SEQC_ + c] = x0s[c][l];
  }
  __syncthreads();
  conv_branch<2>(x0s, ys, cw2, cb2, seq, b, EMB_,          tid);
  conv_branch<3>(x0s, ys, cw3, cb3, seq, b, EMB_ + CD_,    tid);
  conv_branch<8>(x0s, ys, cw8, cb8, seq, b, EMB_ + 2*CD_,  tid);
}

// =====================================================================
// Generic fp32 GEMM: C(M,N) = act(A(M,K) @ B(N,K)^T + bias1 + bias2)
// tile 128x128, K-tile 32, 256 threads, 8x8 micro-tile
// ACT: 0 none, 1 sigmoid, 2 exp
// =====================================================================
template<int ACT>
__global__ __launch_bounds__(256) void k_gemm(
    const float* __restrict__ A, const float* __restrict__ Bm,
    const float* __restrict__ bias1, const float* __restrict__ bias2,
    float* __restrict__ C, int M, int N, int K)
{
  __shared__ float As[32][128];
  __shared__ float Bs[32][128];
  const int m0 = blockIdx.x * 128, n0 = blockIdx.y * 128;
  const int tid = threadIdx.x;
  const int tx = tid & 15, ty = tid >> 4;
  float acc[8][8];
  #pragma unroll
  for (int i = 0; i < 8; ++i)
    #pragma unroll
    for (int j = 0; j < 8; ++j) acc[i][j] = 0.f;

  for (int k0 = 0; k0 < K; k0 += 32) {
    #pragma unroll
    for (int it = 0; it < 16; ++it) {
      int idx = tid + it*256;
      int row = idx & 127, kk = idx >> 7;
      int k = k0 + kk;
      int m = m0 + row;
      As[kk][row] = (k < K && m < M) ? A[(size_t)m*K + k] : 0.f;
      int n = n0 + row;
      Bs[kk][row] = (k < K && n < N) ? Bm[(size_t)n*K + k] : 0.f;
    }
    __syncthreads();
    #pragma unroll
    for (int kk = 0; kk < 32; ++kk) {
      float a[8], bb[8];
      *(float4*)&a[0]  = *(const float4*)&As[kk][ty*8];
      *(float4*)&a[4]  = *(const float4*)&As[kk][ty*8+4];
      *(float4*)&bb[0] = *(const float4*)&Bs[kk][tx*8];
      *(float4*)&bb[4] = *(const float4*)&Bs[kk][tx*8+4];
      #pragma unroll
      for (int i = 0; i < 8; ++i)
        #pragma unroll
        for (int j = 0; j < 8; ++j)
          acc[i][j] = fmaf(a[i], bb[j], acc[i][j]);
    }
    __syncthreads();
  }
  #pragma unroll
  for (int i = 0; i < 8; ++i) {
    int m = m0 + ty*8 + i;
    if (m >= M) continue;
    #pragma unroll
    for (int j4 = 0; j4 < 2; ++j4) {
      int n = n0 + tx*8 + j4*4;
      if (n >= N) continue;              // all N used are multiples of 8
      float vv[4];
      #pragma unroll
      for (int u = 0; u < 4; ++u) {
        float val = acc[i][j4*4+u];
        int nn = n + u;
        if (bias1) val += bias1[nn];
        if (bias2) val += bias2[nn];
        if (ACT == 1) val = sigf(val);
        else if (ACT == 2) val = expf(val);
        vv[u] = val;
      }
      *(float4*)&C[(size_t)m*N + n] = make_float4(vv[0],vv[1],vv[2],vv[3]);
    }
  }
}

// =====================================================================
// transpose whh (400,100) -> whhT (100,400) for both directions
// =====================================================================
__global__ __launch_bounds__(256) void k_transpose(
    const float* __restrict__ whh_f, const float* __restrict__ whh_b,
    float* __restrict__ wtg)
{
  int idx = blockIdx.x*256 + threadIdx.x;
  if (idx >= 80000) return;
  int d = idx / 40000, r = idx - d*40000;
  int j = r / 100, k = r - (r/100)*100;
  const float* src = d ? whh_b : whh_f;
  wtg[(size_t)d*40000 + k*G4_ + j] = src[r];
}

// =====================================================================
// Persistent bidirectional LSTM scan.
// grid (128, 2): blockIdx.x = batch chunk of 8, blockIdx.y = direction.
// whhT staged ONCE in LDS (bf16, [100][512] zero-padded), h/c on-chip.
// dynamic LDS = 102400 + 3200 + 12800 = 118400 B
// =====================================================================
#define NBR 8
__global__ __launch_bounds__(256) void k_scan(
    const float* __restrict__ gx_f, const float* __restrict__ gx_b,
    const float* __restrict__ whhT_g,   // [2][100][400] fp32
    float* __restrict__ hout)           // (B, L, 200): fwd [0,100), bwd [100,200)
{
  extern __shared__ char smem[];
  unsigned short* wT = (unsigned short*)smem;            // [100][512] bf16
  float* h_s = (float*)(smem + 100*512*2);               // [8][100]
  float* g_s = h_s + NBR*H_;                             // [8][400]
  const int dir = blockIdx.y;
  const float* gx = dir ? gx_b : gx_f;
  const int b0 = blockIdx.x * NBR;
  const int tid = threadIdx.x;

  for (int idx = tid; idx < 100*512; idx += 256) {
    int k = idx >> 9, jp = idx & 511;
    float v = (jp < G4_) ? whhT_g[(size_t)dir*40000 + k*G4_ + jp] : 0.f;
    wT[idx] = f2bf(v);
  }
  for (int idx = tid; idx < NBR*H_; idx += 256) h_s[idx] = 0.f;
  float cst[4] = {0.f,0.f,0.f,0.f};
  __syncthreads();

  const int j0 = tid*2;              // gate column pair, [0,512)
  const bool actj = (j0 < G4_);

  for (int t = 0; t < L_; ++t) {
    const int tp = dir ? (L_-1-t) : t;
    // ---- phase A: g = gx + h @ whh^T ----
    float accA[NBR], accB[NBR];
    #pragma unroll
    for (int r = 0; r < NBR; ++r) {
      if (actj) {
        float2 g2 = *(const float2*)&gx[((size_t)(b0+r)*L_ + tp)*G4_ + j0];
        accA[r] = g2.x; accB[r] = g2.y;
      } else { accA[r] = 0.f; accB[r] = 0.f; }
    }
    for (int k4 = 0; k4 < H_; k4 += 4) {
      float w0[4], w1[4];
      #pragma unroll
      for (int i = 0; i < 4; ++i) {
        unsigned int wp = *(const unsigned int*)&wT[(k4+i)*512 + j0];
        w0[i] = bf2f((unsigned short)wp);
        w1[i] = bf2f((unsigned short)(wp >> 16));
      }
      #pragma unroll
      for (int r = 0; r < NBR; ++r) {
        float4 h4 = *(const float4*)&h_s[r*H_ + k4];   // broadcast read
        accA[r] = fmaf(h4.x, w0[0], accA[r]);
        accA[r] = fmaf(h4.y, w0[1], accA[r]);
        accA[r] = fmaf(h4.z, w0[2], accA[r]);
        accA[r] = fmaf(h4.w, w0[3], accA[r]);
        accB[r] = fmaf(h4.x, w1[0], accB[r]);
        accB[r] = fmaf(h4.y, w1[1], accB[r]);
        accB[r] = fmaf(h4.z, w1[2], accB[r]);
        accB[r] = fmaf(h4.w, w1[3], accB[r]);
      }
    }
    if (actj) {
      #pragma unroll
      for (int r = 0; r < NBR; ++r)
        *(float2*)&g_s[r*G4_ + j0] = make_float2(accA[r], accB[r]);
    }
    __syncthreads();
    // ---- phase B: gate nonlinearities, c/h update ----
    #pragma unroll
    for (int s = 0; s < 4; ++s) {
      int idx = tid + s*256;
      if (idx < NBR*H_) {
        int r = idx / H_, kh = idx - r*H_;
        float gi = g_s[r*G4_ + kh];
        float gf = g_s[r*G4_ + 100 + kh];
        float gg = g_s[r*G4_ + 200 + kh];
        float go = g_s[r*G4_ + 300 + kh];
        float cn = sigf(gf)*cst[s] + sigf(gi)*tanhf(gg);
        cst[s] = cn;
        float hn = sigf(go)*tanhf(cn);
        h_s[r*H_ + kh] = hn;
        hout[((size_t)(b0+r)*L_ + tp)*DH_ + dir*H_ + kh] = hn;
      }
    }
    __syncthreads();
  }
}

// =====================================================================
// AFT-full attention: one block per batch element.
// num[i,d] = sum_j exp(pb[i,j]) * ek[j,d]*v[j,d];  den likewise with ek.
// att = sigmoid(q) * num/den.  (sq already holds sigmoid(q).)
// dynamic LDS = 40000 + 40000 + 11200 = 91200 B
// =====================================================================
__global__ __launch_bounds__(256) void k_attn(
    const float* __restrict__ sq, const float* __restrict__ ek, const float* __restrict__ v,
    const float* __restrict__ pos_bias, float* __restrict__ att)
{
  extern __shared__ char smem[];
  float* eks = (float*)smem;          // [50][200]
  float* evs = eks + L_*DH_;          // [50][200]
  float* wpT = evs + L_*DH_;          // [50][56]  wpT[j][i] = exp(pb[i][j])
  const int b = blockIdx.x, tid = threadIdx.x;
  const size_t base = (size_t)b*L_*DH_;
  for (int idx = tid; idx < L_*DH_; idx += 256) {
    float e = ek[base + idx];
    eks[idx] = e;
    evs[idx] = e * v[base + idx];
  }
  for (int idx = tid; idx < 50*56; idx += 256) {
    int j = idx / 56, i = idx - (idx/56)*56;
    wpT[idx] = (i < L_) ? expf(pos_bias[i*L_ + j]) : 0.f;
  }
  __syncthreads();
  if (tid < 175) {
    const int ioct = tid / 25, doct = tid - (tid/25)*25;
    const int i0 = ioct*8, d0 = doct*8;
    float num[8][8], den[8][8];
    #pragma unroll
    for (int i = 0; i < 8; ++i)
      #pragma unroll
      for (int j = 0; j < 8; ++j) { num[i][j] = 0.f; den[i][j] = 0.f; }
    for (int j = 0; j < L_; ++j) {
      float wv8[8], ee8[8], ev8[8];
      *(float4*)&wv8[0] = *(const float4*)&wpT[j*56 + i0];
      *(float4*)&wv8[4] = *(const float4*)&wpT[j*56 + i0 + 4];
      *(float4*)&ee8[0] = *(const float4*)&eks[j*DH_ + d0];
      *(float4*)&ee8[4] = *(const float4*)&eks[j*DH_ + d0 + 4];
      *(float4*)&ev8[0] = *(const float4*)&evs[j*DH_ + d0];
      *(float4*)&ev8[4] = *(const float4*)&evs[j*DH_ + d0 + 4];
      #pragma unroll
      for (int ii = 0; ii < 8; ++ii)
        #pragma unroll
        for (int dd = 0; dd < 8; ++dd) {
          num[ii][dd] = fmaf(wv8[ii], ev8[dd], num[ii][dd]);
          den[ii][dd] = fmaf(wv8[ii], ee8[dd], den[ii][dd]);
        }
    }
    for (int ii = 0; ii < 8; ++ii) {
      int i = i0 + ii;
      if (i >= L_) break;
      #pragma unroll
      for (int d4 = 0; d4 < 2; ++d4) {
        int d = d0 + d4*4;
        float4 s4 = *(const float4*)&sq[base + (size_t)i*DH_ + d];
        float4 o;
        o.x = s4.x * num[ii][d4*4+0] / den[ii][d4*4+0];
        o.y = s4.y * num[ii][d4*4+1] / den[ii][d4*4+1];
        o.z = s4.z * num[ii][d4*4+2] / den[ii][d4*4+2];
        o.w = s4.w * num[ii][d4*4+3] / den[ii][d4*4+3];
        *(float4*)&att[base + (size_t)i*DH_ + d] = o;
      }
    }
  }
}

// =====================================================================
// dense1 split-K: part[s][b][o] = sum_{k in slice s} att[b][k]*dw1[o][k]
// grid (B/16, 8), 256 threads
// =====================================================================
__global__ __launch_bounds__(256) void k_dense1(
    const float* __restrict__ att, const float* __restrict__ dw1,
    float* __restrict__ part)
{
  __shared__ float fs[16][33];
  __shared__ float wsd[32][132];
  const int b0 = blockIdx.x*16;
  const int ks = blockIdx.y*1250;
  const int tid = threadIdx.x;
  const int og = tid & 15, bb = tid >> 4;
  float acc[8];
  #pragma unroll
  for (int u = 0; u < 8; ++u) acc[u] = 0.f;

  for (int k0 = ks; k0 < ks+1250; k0 += 32) {
    const int krem = (ks+1250-k0 < 32) ? (ks+1250-k0) : 32;
    {
      int idx = tid;
      #pragma unroll
      for (int it = 0; it < 2; ++it, idx += 256) {
        int bbs = idx >> 5, kk = idx & 31;
        fs[bbs][kk] = (kk < krem) ? att[(size_t)(b0+bbs)*KD_ + k0+kk] : 0.f;
      }
    }
    #pragma unroll
    for (int it = 0; it < 16; ++it) {
      int idx = tid + it*256;
      int o = idx & 127, kk = idx >> 7;
      wsd[kk][o] = (kk < krem) ? dw1[(size_t)o*KD_ + k0+kk] : 0.f;
    }
    __syncthreads();
    #pragma unroll
    for (int kk = 0; kk < 32; ++kk) {
      float a = fs[bb][kk];
      float w8[8];
      *(float4*)&w8[0] = *(const float4*)&wsd[kk][og*8];
      *(float4*)&w8[4] = *(const float4*)&wsd[kk][og*8+4];
      #pragma unroll
      for (int u = 0; u < 8; ++u) acc[u] = fmaf(a, w8[u], acc[u]);
    }
    __syncthreads();
  }
  float* pp = &part[((size_t)blockIdx.y*B_ + b0 + bb)*NHID_ + og*8];
  *(float4*)&pp[0] = make_float4(acc[0],acc[1],acc[2],acc[3]);
  *(float4*)&pp[4] = make_float4(acc[4],acc[5],acc[6],acc[7]);
}

// =====================================================================
// dense2: reduce split-K partials + bias + relu, then 128->5 + sigmoid
// =====================================================================
__global__ __launch_bounds__(128) void k_dense2(
    const float* __restrict__ part, const float* __restrict__ db1,
    const float* __restrict__ dw2, const float* __restrict__ db2,
    float* __restrict__ out)
{
  __shared__ float hid[NHID_];
  const int b = blockIdx.x, o = threadIdx.x;
  float s = db1[o];
  #pragma unroll
  for (int sl = 0; sl < 8; ++sl) s += part[((size_t)sl*B_ + b)*NHID_ + o];
  hid[o] = fmaxf(s, 0.f);
  __syncthreads();
  if (o < 5) {
    float acc = db2[o];
    for (int j = 0; j < NHID_; ++j) acc = fmaf(hid[j], dw2[o*NHID_ + j], acc);
    out[b*5 + o] = sigf(acc);
  }
}

// =====================================================================
extern "C" void kernel_launch(void* const* d_in, const int* in_sizes, int n_in,
                              void* d_out, int out_size, void* d_ws, size_t ws_size,
                              hipStream_t stream)
{
  const int*   x     = (const int*)  d_in[0];
  const float* emb1  = (const float*)d_in[1];
  const float* emb2  = (const float*)d_in[2];
  const float* cw2   = (const float*)d_in[3];
  const float* cb2   = (const float*)d_in[4];
  const float* cw3   = (const float*)d_in[5];
  const float* cb3   = (const float*)d_in[6];
  const float* cw8   = (const float*)d_in[7];
  const float* cb8   = (const float*)d_in[8];
  const float* wih_f = (const float*)d_in[9];
  const float* whh_f = (const float*)d_in[10];
  const float* bih_f = (const float*)d_in[11];
  const float* bhh_f = (const float*)d_in[12];
  const float* wih_b = (const float*)d_in[13];
  const float* whh_b = (const float*)d_in[14];
  const float* bih_b = (const float*)d_in[15];
  const float* bhh_b = (const float*)d_in[16];
  const float* wq    = (const float*)d_in[17];
  const float* bq    = (const float*)d_in[18];
  const float* wk    = (const float*)d_in[19];
  const float* bk    = (const float*)d_in[20];
  const float* wv    = (const float*)d_in[21];
  const float* bv    = (const float*)d_in[22];
  const float* pos_bias = (const float*)d_in[23];
  const float* dw1   = (const float*)d_in[24];
  const float* db1   = (const float*)d_in[25];
  const float* dw2   = (const float*)d_in[26];
  const float* db2   = (const float*)d_in[27];
  (void)in_sizes; (void)n_in; (void)out_size;

  // ---- workspace layout (floats) ----
  const size_t OFF_SEQ  = 0;                      // (B*L,243)      12,441,600
  const size_t OFF_GXF  = OFF_SEQ + 12441600;     // (B*L,400)      20,480,000
  const size_t OFF_GXB  = OFF_GXF + 20480000;     // (B*L,400)      20,480,000
  const size_t OFF_H    = OFF_GXB + 20480000;     // (B*L,200)      10,240,000
  const size_t OFF_WT   = OFF_H   + 10240000;     // [2][100][400]      80,000
  const size_t OFF_PART = OFF_WT  + 80000;        // [8][B][128]     1,048,576
  const size_t TOTAL    = OFF_PART + 1048576;     // 64,770,176 floats = 259 MB
  if (ws_size < TOTAL*sizeof(float)) return;      // ws too small -> clear fail

  float* ws   = (float*)d_ws;
  float* seq  = ws + OFF_SEQ;
  float* gxf  = ws + OFF_GXF;
  float* gxb  = ws + OFF_GXB;
  float* h    = ws + OFF_H;
  float* wtg  = ws + OFF_WT;
  float* part = ws + OFF_PART;
  // dead-buffer reuse after the scan consumes gx:
  float* sqb  = gxf;                  // sigmoid(q)  (B*L,200)
  float* ekb  = gxf + 10240000;       // exp(k)
  float* vb   = gxb;                  // v
  float* attb = gxb + 10240000;       // att (flat B x 10000)

  hipFuncSetAttribute(reinterpret_cast<const void*>(k_scan),
                      hipFuncAttributeMaxDynamicSharedMemorySize, 118400);
  hipFuncSetAttribute(reinterpret_cast<const void*>(k_attn),
                      hipFuncAttributeMaxDynamicSharedMemorySize, 91200);

  k_embconv<<<dim3(1024), 256, 0, stream>>>(x, emb1, emb2, cw2, cb2, cw3, cb3, cw8, cb8, seq);
  k_gemm<0><<<dim3(400,4), 256, 0, stream>>>(seq, wih_f, bih_f, bhh_f, gxf, 51200, 400, 243);
  k_gemm<0><<<dim3(400,4), 256, 0, stream>>>(seq, wih_b, bih_b, bhh_b, gxb, 51200, 400, 243);
  k_transpose<<<dim3(313), 256, 0, stream>>>(whh_f, whh_b, wtg);
  k_scan<<<dim3(128,2), 256, 118400, stream>>>(gxf, gxb, wtg, h);
  k_gemm<1><<<dim3(400,2), 256, 0, stream>>>(h, wq, bq, nullptr, sqb, 51200, 200, 200);
  k_gemm<2><<<dim3(400,2), 256, 0, stream>>>(h, wk, bk, nullptr, ekb, 51200, 200, 200);
  k_gemm<0><<<dim3(400,2), 256, 0, stream>>>(h, wv, bv, nullptr, vb,  51200, 200, 200);
  k_attn<<<dim3(1024), 256, 91200, stream>>>(sqb, ekb, vb, pos_bias, attb);
  k_dense1<<<dim3(64,8), 256, 0, stream>>>(attb, dw1, part);
  k_dense2<<<dim3(1024), 128, 0, stream>>>(part, db1, dw2, db2, (float*)d_out);
}

// Round 6
// 1428.814 us; speedup vs baseline: 2.4129x; 2.4129x over previous
//
#include <hip/hip_runtime.h>
#include <cstdint>
#include <cstddef>

// ---- model dims ----
#define B_    1024
#define L_    50
#define EMB_  63
#define CD_   60
#define H_    100
#define G4_   400     // 4*H
#define DH_   200     // 2*H
#define NHID_ 128
#define KD_   10000   // L_*DH_

typedef __attribute__((ext_vector_type(8))) short short8;
typedef __attribute__((ext_vector_type(4))) float f32x4;

// ---------- helpers ----------
__device__ __forceinline__ float sigf(float x){ return 1.f/(1.f+expf(-x)); }
__device__ __forceinline__ unsigned short f2bf(float f){
  unsigned int x = __float_as_uint(f);
  unsigned int r = x + 0x7fffu + ((x>>16)&1u);   // RNE
  return (unsigned short)(r>>16);
}
__device__ __forceinline__ float bf2f(unsigned short u){
  return __uint_as_float(((unsigned int)u)<<16);
}
__device__ __forceinline__ void load_lds16(const void* g, void* l){
  // 16B per lane, LDS dst = wave-uniform base + lane*16
  __builtin_amdgcn_global_load_lds((const __attribute__((address_space(1))) void*)g,
                                   (__attribute__((address_space(3))) void*)l, 16, 0, 0);
}

// =====================================================================
// K0: pack weights to bf16 padded layouts + transpose whh
//  wihp  [2][400][256] bf16 (K 243->256 zero pad)
//  bihp  [800] = bih+bhh (fwd | bwd)
//  wqkvp [3][224][224] bf16 (N 200->224 zero rows, K 200->224 zero cols)
//  bqkvp [3][224]
//  whhT  [2][100][400] fp32
// =====================================================================
__global__ __launch_bounds__(256) void k_pack(
    const float* __restrict__ wih_f, const float* __restrict__ bih_f, const float* __restrict__ bhh_f,
    const float* __restrict__ wih_b, const float* __restrict__ bih_b, const float* __restrict__ bhh_b,
    const float* __restrict__ whh_f, const float* __restrict__ whh_b,
    const float* __restrict__ wq, const float* __restrict__ bq,
    const float* __restrict__ wk, const float* __restrict__ bk,
    const float* __restrict__ wv, const float* __restrict__ bv,
    unsigned short* __restrict__ wihp, float* __restrict__ bihp,
    unsigned short* __restrict__ wqkvp, float* __restrict__ bqkvp,
    float* __restrict__ whhT)
{
  int i = blockIdx.x*256 + threadIdx.x;
  if (i < 204800) {
    int d = i / 102400, rem = i % 102400, r = rem >> 8, k = rem & 255;
    const float* src = d ? wih_b : wih_f;
    wihp[i] = f2bf((k < 243) ? src[r*243 + k] : 0.f);
  } else if ((i -= 204800) < 800) {
    bihp[i] = (i < 400) ? (bih_f[i] + bhh_f[i]) : (bih_b[i-400] + bhh_b[i-400]);
  } else if ((i -= 800) < 150528) {
    int s = i / 50176, rem = i % 50176, n = rem / 224, k = rem % 224;
    const float* w = (s==0) ? wq : (s==1) ? wk : wv;
    wqkvp[i] = f2bf((n < 200 && k < 200) ? w[n*200 + k] : 0.f);
  } else if ((i -= 150528) < 672) {
    int s = i / 224, n = i % 224;
    const float* bb = (s==0) ? bq : (s==1) ? bk : bv;
    bqkvp[i] = (n < 200) ? bb[n] : 0.f;
  } else if ((i -= 672) < 80000) {
    int d = i / 40000, r = i % 40000, j = r / 100, k = r % 100;
    const float* src = d ? whh_b : whh_f;
    whhT[(size_t)d*40000 + k*G4_ + j] = src[r];
  }
}

// =====================================================================
// K1: embedding + 3 conv branches + relu + maxpool + pad -> seq bf16 [B*L][256]
// =====================================================================
template<int KH>
__device__ __forceinline__ void conv_branch(
    const float (&x0s)[EMB_][64], float (&ys)[CD_][49],
    const float* __restrict__ w, const float* __restrict__ cb,
    unsigned short* __restrict__ seq, int b, int co, int tid)
{
  const int Lc = 51 - KH;
  const int Lp = Lc - 2;
  const int nt8 = (Lc + 7) >> 3;
  for (int task = tid; task < CD_*nt8; task += 256) {
    int o = task / nt8, tc = (task % nt8) << 3;
    float acc[8];
    float bb = cb[o];
    #pragma unroll
    for (int j = 0; j < 8; ++j) acc[j] = bb;
    for (int c = 0; c < EMB_; ++c) {
      float xw[16];
      const float* xr = &x0s[c][tc];
      *(float4*)&xw[0]  = *(const float4*)&xr[0];
      *(float4*)&xw[4]  = *(const float4*)&xr[4];
      *(float4*)&xw[8]  = *(const float4*)&xr[8];
      *(float4*)&xw[12] = *(const float4*)&xr[12];
      const float* wr = &w[(o*EMB_ + c)*KH];
      float wvv[KH];
      #pragma unroll
      for (int tau = 0; tau < KH; ++tau) wvv[tau] = wr[tau];
      #pragma unroll
      for (int tau = 0; tau < KH; ++tau) {
        #pragma unroll
        for (int j = 0; j < 8; ++j) acc[j] = fmaf(xw[tau+j], wvv[tau], acc[j]);
      }
    }
    #pragma unroll
    for (int j = 0; j < 8; ++j) {
      int t = tc + j;
      if (t < Lc) ys[o][t] = fmaxf(acc[j], 0.f);
    }
  }
  __syncthreads();
  for (int idx = tid; idx < L_*CD_; idx += 256) {
    int l = idx / CD_, o = idx - (idx/CD_)*CD_;
    float vm = 0.f;
    if (l < Lp) {
      int lo = (l-1 < 0) ? 0 : l-1;
      int hi = (l+3 >= Lc) ? Lc-1 : l+3;
      for (int t = lo; t <= hi; ++t) vm = fmaxf(vm, ys[o][t]);
    }
    seq[((size_t)b*L_ + l)*256 + co + o] = f2bf(vm);
  }
  __syncthreads();
}

__global__ __launch_bounds__(256) void k_embconv(
    const int* __restrict__ x, const float* __restrict__ emb1, const float* __restrict__ emb2,
    const float* __restrict__ cw2, const float* __restrict__ cb2,
    const float* __restrict__ cw3, const float* __restrict__ cb3,
    const float* __restrict__ cw8, const float* __restrict__ cb8,
    unsigned short* __restrict__ seq)
{
  __shared__ float x0s[EMB_][64];
  __shared__ float ys[CD_][49];
  __shared__ int   xs[L_];
  const int b = blockIdx.x, tid = threadIdx.x;
  if (tid < L_) xs[tid] = x[b*L_ + tid];
  __syncthreads();
  for (int idx = tid; idx < EMB_*64; idx += 256) {
    int c = idx >> 6, l = idx & 63;
    float v = 0.f;
    if (l < L_) { int e = xs[l]; v = (c < 21) ? emb1[e*21 + c] : emb2[e*42 + (c-21)]; }
    x0s[c][l] = v;
  }
  __syncthreads();
  // x0 channels [0,63) + K-pad cols [243,256)
  for (int idx = tid; idx < L_*EMB_; idx += 256) {
    int l = idx / EMB_, c = idx - (idx/EMB_)*EMB_;
    seq[((size_t)b*L_ + l)*256 + c] = f2bf(x0s[c][l]);
  }
  for (int idx = tid; idx < L_*13; idx += 256) {
    int l = idx / 13, p = idx - (idx/13)*13;
    seq[((size_t)b*L_ + l)*256 + 243 + p] = 0;
  }
  __syncthreads();
  conv_branch<2>(x0s, ys, cw2, cb2, seq, b, EMB_,          tid);
  conv_branch<3>(x0s, ys, cw3, cb3, seq, b, EMB_ + CD_,    tid);
  conv_branch<8>(x0s, ys, cw8, cb8, seq, b, EMB_ + 2*CD_,  tid);
}

// =====================================================================
// bf16 MFMA GEMM: C(M, N) = act(A(M,KA) @ W(N,KA)^T + bias)
// BM=128, BN=NF*16, BK=32. 256 thr = 4 waves, each wave: 32 rows x BN cols.
// A-tile LDS: [4][128][8] (k-octet major), W-tile LDS: [BN][4][8].
// OUTMODE 0: fp32 store, mask col<Nreal; 1: bf16 store unmasked.
// ACT 0 none, 1 sigmoid, 2 exp
// =====================================================================
template<int NF, int KSTEPS, int ACT, int OUTMODE>
__global__ __launch_bounds__(256) void k_gemm_mfma(
    const unsigned short* __restrict__ A,
    const unsigned short* __restrict__ W,
    const float* __restrict__ bias,
    void* __restrict__ C, int Nstride, int Nreal)
{
  constexpr int BN = NF*16;
  constexpr int KA = KSTEPS*32;
  constexpr int TU = 512 + BN*4;       // 16B staging units per K-tile
  __shared__ __attribute__((aligned(16))) unsigned short As[512*8];
  __shared__ __attribute__((aligned(16))) unsigned short Ws[BN*32];
  const int tid = threadIdx.x;
  const int lane = tid & 63, w = tid >> 6;
  const int m0 = blockIdx.x*128, n0 = blockIdx.y*BN;
  const int c = lane >> 4, r16 = lane & 15;
  f32x4 acc[2][NF];
  #pragma unroll
  for (int i = 0; i < 2; ++i)
    #pragma unroll
    for (int j = 0; j < NF; ++j) acc[i][j] = (f32x4){0.f,0.f,0.f,0.f};

  for (int ks = 0; ks < KSTEPS; ++ks) {
    const int k0 = ks*32;
    #pragma unroll
    for (int it = 0; it*256 < TU; ++it) {
      const int u0 = it*256 + w*64;           // wave-uniform
      if (u0 < TU) {
        if (u0 < 512) {
          const int u = u0 + lane;
          const int cc = u >> 7, row = u & 127;
          load_lds16(&A[(size_t)(m0+row)*KA + k0 + cc*8], (char*)As + (size_t)u0*16);
        } else {
          const int v2 = u0 - 512 + lane;
          const int n = v2 >> 2, cc = v2 & 3;
          load_lds16(&W[(size_t)(n0+n)*KA + k0 + cc*8], (char*)Ws + (size_t)(u0-512)*16);
        }
      }
    }
    __syncthreads();   // compiler drains vmcnt before barrier
    short8 a0 = *(const short8*)&As[(c*128 + w*32 + r16)*8];
    short8 a1 = *(const short8*)&As[(c*128 + w*32 + 16 + r16)*8];
    #pragma unroll
    for (int nf = 0; nf < NF; ++nf) {
      short8 bfr = *(const short8*)&Ws[((nf*16 + r16)*4 + c)*8];
      acc[0][nf] = __builtin_amdgcn_mfma_f32_16x16x32_bf16(a0, bfr, acc[0][nf], 0, 0, 0);
      acc[1][nf] = __builtin_amdgcn_mfma_f32_16x16x32_bf16(a1, bfr, acc[1][nf], 0, 0, 0);
    }
    __syncthreads();
  }
  // epilogue: C/D frag mapping col=lane&15, row=(lane>>4)*4+r
  const int rg = lane >> 4;
  #pragma unroll
  for (int mf = 0; mf < 2; ++mf) {
    #pragma unroll
    for (int nf = 0; nf < NF; ++nf) {
      const int colp = n0 + nf*16 + r16;
      const float bs = bias[colp];
      #pragma unroll
      for (int r = 0; r < 4; ++r) {
        const int row = m0 + w*32 + mf*16 + rg*4 + r;
        float val = acc[mf][nf][r] + bs;
        if (ACT == 1) val = sigf(val);
        else if (ACT == 2) val = expf(val);
        if (OUTMODE == 0) {
          if (colp < Nreal) ((float*)C)[(size_t)row*Nstride + colp] = val;
        } else {
          ((unsigned short*)C)[(size_t)row*Nstride + colp] = f2bf(val);
        }
      }
    }
  }
}

// =====================================================================
// Persistent bidirectional LSTM scan (gx bf16 in, h bf16 out)
// grid (128, 2). whhT staged once in LDS (bf16 [100][512]).
// dynamic LDS = 102400 + 3200 + 12800 = 118400 B
// =====================================================================
#define NBR 8
__global__ __launch_bounds__(256) void k_scan(
    const unsigned short* __restrict__ gx,   // [B*L][800] bf16: fwd cols [0,400), bwd [400,800)
    const float* __restrict__ whhT_g,        // [2][100][400] fp32
    unsigned short* __restrict__ hout)       // [B*L][224] bf16: fwd [0,100), bwd [100,200), pad [200,224)
{
  extern __shared__ char smem[];
  unsigned short* wT = (unsigned short*)smem;            // [100][512] bf16
  float* h_s = (float*)(smem + 100*512*2);               // [8][100]
  float* g_s = h_s + NBR*H_;                             // [8][400]
  const int dir = blockIdx.y;
  const int b0 = blockIdx.x * NBR;
  const int tid = threadIdx.x;

  for (int idx = tid; idx < 100*512; idx += 256) {
    int k = idx >> 9, jp = idx & 511;
    float v = (jp < G4_) ? whhT_g[(size_t)dir*40000 + k*G4_ + jp] : 0.f;
    wT[idx] = f2bf(v);
  }
  for (int idx = tid; idx < NBR*H_; idx += 256) h_s[idx] = 0.f;
  float cst[4] = {0.f,0.f,0.f,0.f};
  __syncthreads();

  const int j0 = tid*2;
  const bool actj = (j0 < G4_);

  for (int t = 0; t < L_; ++t) {
    const int tp = dir ? (L_-1-t) : t;
    float accA[NBR], accB[NBR];
    #pragma unroll
    for (int r = 0; r < NBR; ++r) {
      if (actj) {
        unsigned int g2 = *(const unsigned int*)&gx[((size_t)(b0+r)*L_ + tp)*800 + dir*400 + j0];
        accA[r] = bf2f((unsigned short)g2);
        accB[r] = bf2f((unsigned short)(g2 >> 16));
      } else { accA[r] = 0.f; accB[r] = 0.f; }
    }
    for (int k4 = 0; k4 < H_; k4 += 4) {
      float w0[4], w1[4];
      #pragma unroll
      for (int i = 0; i < 4; ++i) {
        unsigned int wp = *(const unsigned int*)&wT[(k4+i)*512 + j0];
        w0[i] = bf2f((unsigned short)wp);
        w1[i] = bf2f((unsigned short)(wp >> 16));
      }
      #pragma unroll
      for (int r = 0; r < NBR; ++r) {
        float4 h4 = *(const float4*)&h_s[r*H_ + k4];
        accA[r] = fmaf(h4.x, w0[0], accA[r]);
        accA[r] = fmaf(h4.y, w0[1], accA[r]);
        accA[r] = fmaf(h4.z, w0[2], accA[r]);
        accA[r] = fmaf(h4.w, w0[3], accA[r]);
        accB[r] = fmaf(h4.x, w1[0], accB[r]);
        accB[r] = fmaf(h4.y, w1[1], accB[r]);
        accB[r] = fmaf(h4.z, w1[2], accB[r]);
        accB[r] = fmaf(h4.w, w1[3], accB[r]);
      }
    }
    if (actj) {
      #pragma unroll
      for (int r = 0; r < NBR; ++r)
        *(float2*)&g_s[r*G4_ + j0] = make_float2(accA[r], accB[r]);
    }
    __syncthreads();
    #pragma unroll
    for (int s = 0; s < 4; ++s) {
      int idx = tid + s*256;
      if (idx < NBR*H_) {
        int r = idx / H_, kh = idx - r*H_;
        float gi = g_s[r*G4_ + kh];
        float gf = g_s[r*G4_ + 100 + kh];
        float gg = g_s[r*G4_ + 200 + kh];
        float go = g_s[r*G4_ + 300 + kh];
        float cn = sigf(gf)*cst[s] + sigf(gi)*tanhf(gg);
        cst[s] = cn;
        float hn = sigf(go)*tanhf(cn);
        h_s[r*H_ + kh] = hn;
        hout[((size_t)(b0+r)*L_ + tp)*224 + dir*H_ + kh] = f2bf(hn);
      }
    }
    if (dir == 0) {
      for (int idx = tid; idx < NBR*24; idx += 256) {
        int r = idx / 24, p = idx - (idx/24)*24;
        hout[((size_t)(b0+r)*L_ + tp)*224 + 200 + p] = 0;
      }
    }
    __syncthreads();
  }
}

// =====================================================================
// AFT attention: one block per batch element, fp32 in/out
// dynamic LDS = 40000 + 40000 + 11200 = 91200 B
// =====================================================================
__global__ __launch_bounds__(256) void k_attn(
    const float* __restrict__ sq, const float* __restrict__ ek, const float* __restrict__ v,
    const float* __restrict__ pos_bias, float* __restrict__ att)
{
  extern __shared__ char smem[];
  float* eks = (float*)smem;          // [50][200]
  float* evs = eks + L_*DH_;          // [50][200]
  float* wpT = evs + L_*DH_;          // [50][56]
  const int b = blockIdx.x, tid = threadIdx.x;
  const size_t base = (size_t)b*L_*DH_;
  for (int idx = tid; idx < L_*DH_; idx += 256) {
    float e = ek[base + idx];
    eks[idx] = e;
    evs[idx] = e * v[base + idx];
  }
  for (int idx = tid; idx < 50*56; idx += 256) {
    int j = idx / 56, i = idx - (idx/56)*56;
    wpT[idx] = (i < L_) ? expf(pos_bias[i*L_ + j]) : 0.f;
  }
  __syncthreads();
  if (tid < 175) {
    const int ioct = tid / 25, doct = tid - (tid/25)*25;
    const int i0 = ioct*8, d0 = doct*8;
    float num[8][8], den[8][8];
    #pragma unroll
    for (int i = 0; i < 8; ++i)
      #pragma unroll
      for (int j = 0; j < 8; ++j) { num[i][j] = 0.f; den[i][j] = 0.f; }
    for (int j = 0; j < L_; ++j) {
      float wv8[8], ee8[8], ev8[8];
      *(float4*)&wv8[0] = *(const float4*)&wpT[j*56 + i0];
      *(float4*)&wv8[4] = *(const float4*)&wpT[j*56 + i0 + 4];
      *(float4*)&ee8[0] = *(const float4*)&eks[j*DH_ + d0];
      *(float4*)&ee8[4] = *(const float4*)&eks[j*DH_ + d0 + 4];
      *(float4*)&ev8[0] = *(const float4*)&evs[j*DH_ + d0];
      *(float4*)&ev8[4] = *(const float4*)&evs[j*DH_ + d0 + 4];
      #pragma unroll
      for (int ii = 0; ii < 8; ++ii)
        #pragma unroll
        for (int dd = 0; dd < 8; ++dd) {
          num[ii][dd] = fmaf(wv8[ii], ev8[dd], num[ii][dd]);
          den[ii][dd] = fmaf(wv8[ii], ee8[dd], den[ii][dd]);
        }
    }
    for (int ii = 0; ii < 8; ++ii) {
      int i = i0 + ii;
      if (i >= L_) break;
      #pragma unroll
      for (int d4 = 0; d4 < 2; ++d4) {
        int d = d0 + d4*4;
        float4 s4 = *(const float4*)&sq[base + (size_t)i*DH_ + d];
        float4 o;
        o.x = s4.x * num[ii][d4*4+0] / den[ii][d4*4+0];
        o.y = s4.y * num[ii][d4*4+1] / den[ii][d4*4+1];
        o.z = s4.z * num[ii][d4*4+2] / den[ii][d4*4+2];
        o.w = s4.w * num[ii][d4*4+3] / den[ii][d4*4+3];
        *(float4*)&att[base + (size_t)i*DH_ + d] = o;
      }
    }
  }
}

// =====================================================================
// dense1 split-K (fp32)
// =====================================================================
__global__ __launch_bounds__(256) void k_dense1(
    const float* __restrict__ att, const float* __restrict__ dw1,
    float* __restrict__ part)
{
  __shared__ float fs[16][33];
  __shared__ float wsd[32][132];
  const int b0 = blockIdx.x*16;
  const int ks = blockIdx.y*1250;
  const int tid = threadIdx.x;
  const int og = tid & 15, bb = tid >> 4;
  float acc[8];
  #pragma unroll
  for (int u = 0; u < 8; ++u) acc[u] = 0.f;

  for (int k0 = ks; k0 < ks+1250; k0 += 32) {
    const int krem = (ks+1250-k0 < 32) ? (ks+1250-k0) : 32;
    {
      int idx = tid;
      #pragma unroll
      for (int it = 0; it < 2; ++it, idx += 256) {
        int bbs = idx >> 5, kk = idx & 31;
        fs[bbs][kk] = (kk < krem) ? att[(size_t)(b0+bbs)*KD_ + k0+kk] : 0.f;
      }
    }
    #pragma unroll
    for (int it = 0; it < 16; ++it) {
      int idx = tid + it*256;
      int o = idx & 127, kk = idx >> 7;
      wsd[kk][o] = (kk < krem) ? dw1[(size_t)o*KD_ + k0+kk] : 0.f;
    }
    __syncthreads();
    #pragma unroll
    for (int kk = 0; kk < 32; ++kk) {
      float a = fs[bb][kk];
      float w8[8];
      *(float4*)&w8[0] = *(const float4*)&wsd[kk][og*8];
      *(float4*)&w8[4] = *(const float4*)&wsd[kk][og*8+4];
      #pragma unroll
      for (int u = 0; u < 8; ++u) acc[u] = fmaf(a, w8[u], acc[u]);
    }
    __syncthreads();
  }
  float* pp = &part[((size_t)blockIdx.y*B_ + b0 + bb)*NHID_ + og*8];
  *(float4*)&pp[0] = make_float4(acc[0],acc[1],acc[2],acc[3]);
  *(float4*)&pp[4] = make_float4(acc[4],acc[5],acc[6],acc[7]);
}

// =====================================================================
// dense2
// =====================================================================
__global__ __launch_bounds__(128) void k_dense2(
    const float* __restrict__ part, const float* __restrict__ db1,
    const float* __restrict__ dw2, const float* __restrict__ db2,
    float* __restrict__ out)
{
  __shared__ float hid[NHID_];
  const int b = blockIdx.x, o = threadIdx.x;
  float s = db1[o];
  #pragma unroll
  for (int sl = 0; sl < 8; ++sl) s += part[((size_t)sl*B_ + b)*NHID_ + o];
  hid[o] = fmaxf(s, 0.f);
  __syncthreads();
  if (o < 5) {
    float acc = db2[o];
    for (int j = 0; j < NHID_; ++j) acc = fmaf(hid[j], dw2[o*NHID_ + j], acc);
    out[b*5 + o] = sigf(acc);
  }
}

// =====================================================================
extern "C" void kernel_launch(void* const* d_in, const int* in_sizes, int n_in,
                              void* d_out, int out_size, void* d_ws, size_t ws_size,
                              hipStream_t stream)
{
  const int*   x     = (const int*)  d_in[0];
  const float* emb1  = (const float*)d_in[1];
  const float* emb2  = (const float*)d_in[2];
  const float* cw2   = (const float*)d_in[3];
  const float* cb2   = (const float*)d_in[4];
  const float* cw3   = (const float*)d_in[5];
  const float* cb3   = (const float*)d_in[6];
  const float* cw8   = (const float*)d_in[7];
  const float* cb8   = (const float*)d_in[8];
  const float* wih_f = (const float*)d_in[9];
  const float* whh_f = (const float*)d_in[10];
  const float* bih_f = (const float*)d_in[11];
  const float* bhh_f = (const float*)d_in[12];
  const float* wih_b = (const float*)d_in[13];
  const float* whh_b = (const float*)d_in[14];
  const float* bih_b = (const float*)d_in[15];
  const float* bhh_b = (const float*)d_in[16];
  const float* wq    = (const float*)d_in[17];
  const float* bq    = (const float*)d_in[18];
  const float* wk    = (const float*)d_in[19];
  const float* bk    = (const float*)d_in[20];
  const float* wv    = (const float*)d_in[21];
  const float* bv    = (const float*)d_in[22];
  const float* pos_bias = (const float*)d_in[23];
  const float* dw1   = (const float*)d_in[24];
  const float* db1   = (const float*)d_in[25];
  const float* dw2   = (const float*)d_in[26];
  const float* db2   = (const float*)d_in[27];
  (void)in_sizes; (void)n_in; (void)out_size;

  // ---- workspace layout (bytes, 256-aligned) ----
  char* base = (char*)d_ws;
  size_t off = 0;
  auto alloc = [&](size_t bytes) -> char* {
    char* p = base + off;
    off = (off + bytes + 255) & ~(size_t)255;
    return p;
  };
  unsigned short* seqb  = (unsigned short*)alloc(51200UL*256*2);   // 26.2 MB
  unsigned short* gxb   = (unsigned short*)alloc(51200UL*800*2);   // 81.9 MB
  unsigned short* hb    = (unsigned short*)alloc(51200UL*224*2);   // 22.9 MB
  float*          sqb   = (float*)alloc(51200UL*200*4);            // 41.0 MB
  float*          ekb   = (float*)alloc(51200UL*200*4);            // 41.0 MB
  float*          vb    = (float*)alloc(51200UL*200*4);            // 41.0 MB
  unsigned short* wihp  = (unsigned short*)alloc(204800UL*2);
  float*          bihp  = (float*)alloc(800UL*4);
  unsigned short* wqkvp = (unsigned short*)alloc(150528UL*2);
  float*          bqkvp = (float*)alloc(672UL*4);
  float*          whhT  = (float*)alloc(80000UL*4);
  if (off > ws_size) return;                 // ~255 MB total
  float* attb = (float*)gxb;                 // overlay: gx dead after scan
  float* part = (float*)seqb;                // overlay: seq dead after gx GEMM

  hipFuncSetAttribute(reinterpret_cast<const void*>(k_scan),
                      hipFuncAttributeMaxDynamicSharedMemorySize, 118400);
  hipFuncSetAttribute(reinterpret_cast<const void*>(k_attn),
                      hipFuncAttributeMaxDynamicSharedMemorySize, 91200);

  k_pack<<<dim3(1707), 256, 0, stream>>>(wih_f, bih_f, bhh_f, wih_b, bih_b, bhh_b,
                                         whh_f, whh_b, wq, bq, wk, bk, wv, bv,
                                         wihp, bihp, wqkvp, bqkvp, whhT);
  k_embconv<<<dim3(1024), 256, 0, stream>>>(x, emb1, emb2, cw2, cb2, cw3, cb3, cw8, cb8, seqb);
  // gx = seq @ [wih_f|wih_b]^T + biases  -> bf16 (M=51200, N=800, K=256)
  k_gemm_mfma<5, 8, 0, 1><<<dim3(400, 10), 256, 0, stream>>>(seqb, wihp, bihp, gxb, 800, 800);
  k_scan<<<dim3(128, 2), 256, 118400, stream>>>(gxb, whhT, hb);
  // q/k/v GEMMs (M=51200, N=200 pad 224, K=224), epilogue sigmoid/exp/none
  k_gemm_mfma<7, 7, 1, 0><<<dim3(400, 2), 256, 0, stream>>>(hb, wqkvp,          bqkvp,       sqb, 200, 200);
  k_gemm_mfma<7, 7, 2, 0><<<dim3(400, 2), 256, 0, stream>>>(hb, wqkvp + 50176,  bqkvp + 224, ekb, 200, 200);
  k_gemm_mfma<7, 7, 0, 0><<<dim3(400, 2), 256, 0, stream>>>(hb, wqkvp + 100352, bqkvp + 448, vb,  200, 200);
  k_attn<<<dim3(1024), 256, 91200, stream>>>(sqb, ekb, vb, pos_bias, attb);
  k_dense1<<<dim3(64, 8), 256, 0, stream>>>(attb, dw1, part);
  k_dense2<<<dim3(1024), 128, 0, stream>>>(part, db1, dw2, db2, (float*)d_out);
}

// Round 7
// 839.285 us; speedup vs baseline: 4.1078x; 1.7024x over previous
//
#include <hip/hip_runtime.h>
#include <cstdint>
#include <cstddef>

// ---- model dims ----
#define B_    1024
#define L_    50
#define EMB_  63
#define CD_   60
#define H_    100
#define G4_   400     // 4*H
#define DH_   200     // 2*H
#define NHID_ 128
#define KD_   10000   // L_*DH_

typedef __attribute__((ext_vector_type(8))) short short8;
typedef __attribute__((ext_vector_type(4))) float f32x4;

// ---------- helpers ----------
__device__ __forceinline__ float sigf(float x){ return 1.f/(1.f+expf(-x)); }
__device__ __forceinline__ unsigned short f2bf(float f){
  unsigned int x = __float_as_uint(f);
  unsigned int r = x + 0x7fffu + ((x>>16)&1u);   // RNE
  return (unsigned short)(r>>16);
}
__device__ __forceinline__ float bf2f(unsigned short u){
  return __uint_as_float(((unsigned int)u)<<16);
}
__device__ __forceinline__ void load_lds16(const void* g, void* l){
  // 16B per lane, LDS dst = wave-uniform base + lane*16
  __builtin_amdgcn_global_load_lds((const __attribute__((address_space(1))) void*)g,
                                   (__attribute__((address_space(3))) void*)l, 16, 0, 0);
}

// =====================================================================
// K0: pack weights to bf16 padded layouts
//  wihp  [2][400][256] bf16 (K 243->256 zero pad)
//  bihp  [800] = bih+bhh (fwd | bwd)
//  wqkvp [3][224][224] bf16 (N 200->224 zero rows, K 200->224 zero cols)
//  bqkvp [3][224]
//  whhpk [2][448][128] bf16 (N 400->448 zero rows, K 100->128 zero cols)
// =====================================================================
__global__ __launch_bounds__(256) void k_pack(
    const float* __restrict__ wih_f, const float* __restrict__ bih_f, const float* __restrict__ bhh_f,
    const float* __restrict__ wih_b, const float* __restrict__ bih_b, const float* __restrict__ bhh_b,
    const float* __restrict__ whh_f, const float* __restrict__ whh_b,
    const float* __restrict__ wq, const float* __restrict__ bq,
    const float* __restrict__ wk, const float* __restrict__ bk,
    const float* __restrict__ wv, const float* __restrict__ bv,
    unsigned short* __restrict__ wihp, float* __restrict__ bihp,
    unsigned short* __restrict__ wqkvp, float* __restrict__ bqkvp,
    unsigned short* __restrict__ whhpk)
{
  int i = blockIdx.x*256 + threadIdx.x;
  if (i < 204800) {
    int d = i / 102400, rem = i % 102400, r = rem >> 8, k = rem & 255;
    const float* src = d ? wih_b : wih_f;
    wihp[i] = f2bf((k < 243) ? src[r*243 + k] : 0.f);
  } else if ((i -= 204800) < 800) {
    bihp[i] = (i < 400) ? (bih_f[i] + bhh_f[i]) : (bih_b[i-400] + bhh_b[i-400]);
  } else if ((i -= 800) < 150528) {
    int s = i / 50176, rem = i % 50176, n = rem / 224, k = rem % 224;
    const float* w = (s==0) ? wq : (s==1) ? wk : wv;
    wqkvp[i] = f2bf((n < 200 && k < 200) ? w[n*200 + k] : 0.f);
  } else if ((i -= 150528) < 672) {
    int s = i / 224, n = i % 224;
    const float* bb = (s==0) ? bq : (s==1) ? bk : bv;
    bqkvp[i] = (n < 200) ? bb[n] : 0.f;
  } else if ((i -= 672) < 114688) {
    int d = i / 57344, rem = i % 57344, n = rem >> 7, k = rem & 127;
    const float* src = d ? whh_b : whh_f;
    whhpk[i] = f2bf((n < 400 && k < 100) ? src[n*100 + k] : 0.f);
  }
}

// =====================================================================
// K1: embedding + 3 conv branches + relu + maxpool + pad -> seq bf16 [B*L][256]
// =====================================================================
template<int KH>
__device__ __forceinline__ void conv_branch(
    const float (&x0s)[EMB_][64], float (&ys)[CD_][49],
    const float* __restrict__ w, const float* __restrict__ cb,
    unsigned short* __restrict__ seq, int b, int co, int tid)
{
  const int Lc = 51 - KH;
  const int Lp = Lc - 2;
  const int nt8 = (Lc + 7) >> 3;
  for (int task = tid; task < CD_*nt8; task += 256) {
    int o = task / nt8, tc = (task % nt8) << 3;
    float acc[8];
    float bb = cb[o];
    #pragma unroll
    for (int j = 0; j < 8; ++j) acc[j] = bb;
    for (int c = 0; c < EMB_; ++c) {
      float xw[16];
      const float* xr = &x0s[c][tc];
      *(float4*)&xw[0]  = *(const float4*)&xr[0];
      *(float4*)&xw[4]  = *(const float4*)&xr[4];
      *(float4*)&xw[8]  = *(const float4*)&xr[8];
      *(float4*)&xw[12] = *(const float4*)&xr[12];
      const float* wr = &w[(o*EMB_ + c)*KH];
      float wvv[KH];
      #pragma unroll
      for (int tau = 0; tau < KH; ++tau) wvv[tau] = wr[tau];
      #pragma unroll
      for (int tau = 0; tau < KH; ++tau) {
        #pragma unroll
        for (int j = 0; j < 8; ++j) acc[j] = fmaf(xw[tau+j], wvv[tau], acc[j]);
      }
    }
    #pragma unroll
    for (int j = 0; j < 8; ++j) {
      int t = tc + j;
      if (t < Lc) ys[o][t] = fmaxf(acc[j], 0.f);
    }
  }
  __syncthreads();
  for (int idx = tid; idx < L_*CD_; idx += 256) {
    int l = idx / CD_, o = idx - (idx/CD_)*CD_;
    float vm = 0.f;
    if (l < Lp) {
      int lo = (l-1 < 0) ? 0 : l-1;
      int hi = (l+3 >= Lc) ? Lc-1 : l+3;
      for (int t = lo; t <= hi; ++t) vm = fmaxf(vm, ys[o][t]);
    }
    seq[((size_t)b*L_ + l)*256 + co + o] = f2bf(vm);
  }
  __syncthreads();
}

__global__ __launch_bounds__(256) void k_embconv(
    const int* __restrict__ x, const float* __restrict__ emb1, const float* __restrict__ emb2,
    const float* __restrict__ cw2, const float* __restrict__ cb2,
    const float* __restrict__ cw3, const float* __restrict__ cb3,
    const float* __restrict__ cw8, const float* __restrict__ cb8,
    unsigned short* __restrict__ seq)
{
  __shared__ float x0s[EMB_][64];
  __shared__ float ys[CD_][49];
  __shared__ int   xs[L_];
  const int b = blockIdx.x, tid = threadIdx.x;
  if (tid < L_) xs[tid] = x[b*L_ + tid];
  __syncthreads();
  for (int idx = tid; idx < EMB_*64; idx += 256) {
    int c = idx >> 6, l = idx & 63;
    float v = 0.f;
    if (l < L_) { int e = xs[l]; v = (c < 21) ? emb1[e*21 + c] : emb2[e*42 + (c-21)]; }
    x0s[c][l] = v;
  }
  __syncthreads();
  // x0 channels [0,63) + K-pad cols [243,256)
  for (int idx = tid; idx < L_*EMB_; idx += 256) {
    int l = idx / EMB_, c = idx - (idx/EMB_)*EMB_;
    seq[((size_t)b*L_ + l)*256 + c] = f2bf(x0s[c][l]);
  }
  for (int idx = tid; idx < L_*13; idx += 256) {
    int l = idx / 13, p = idx - (idx/13)*13;
    seq[((size_t)b*L_ + l)*256 + 243 + p] = 0;
  }
  __syncthreads();
  conv_branch<2>(x0s, ys, cw2, cb2, seq, b, EMB_,          tid);
  conv_branch<3>(x0s, ys, cw3, cb3, seq, b, EMB_ + CD_,    tid);
  conv_branch<8>(x0s, ys, cw8, cb8, seq, b, EMB_ + 2*CD_,  tid);
}

// =====================================================================
// bf16 MFMA GEMM: C(M, N) = act(A(M,KA) @ W(N,KA)^T + bias)
// BM=128, BN=NF*16, BK=32. 256 thr = 4 waves, each wave: 32 rows x BN cols.
// OUTMODE 0: fp32 store, mask col<Nreal; 1: bf16 store unmasked.
// ACT 0 none, 1 sigmoid, 2 exp
// =====================================================================
template<int NF, int KSTEPS, int ACT, int OUTMODE>
__global__ __launch_bounds__(256) void k_gemm_mfma(
    const unsigned short* __restrict__ A,
    const unsigned short* __restrict__ W,
    const float* __restrict__ bias,
    void* __restrict__ C, int Nstride, int Nreal)
{
  constexpr int BN = NF*16;
  constexpr int KA = KSTEPS*32;
  constexpr int TU = 512 + BN*4;       // 16B staging units per K-tile
  __shared__ __attribute__((aligned(16))) unsigned short As[512*8];
  __shared__ __attribute__((aligned(16))) unsigned short Ws[BN*32];
  const int tid = threadIdx.x;
  const int lane = tid & 63, w = tid >> 6;
  const int m0 = blockIdx.x*128, n0 = blockIdx.y*BN;
  const int c = lane >> 4, r16 = lane & 15;
  f32x4 acc[2][NF];
  #pragma unroll
  for (int i = 0; i < 2; ++i)
    #pragma unroll
    for (int j = 0; j < NF; ++j) acc[i][j] = (f32x4){0.f,0.f,0.f,0.f};

  for (int ks = 0; ks < KSTEPS; ++ks) {
    const int k0 = ks*32;
    #pragma unroll
    for (int it = 0; it*256 < TU; ++it) {
      const int u0 = it*256 + w*64;           // wave-uniform
      if (u0 < TU) {
        if (u0 < 512) {
          const int u = u0 + lane;
          const int cc = u >> 7, row = u & 127;
          load_lds16(&A[(size_t)(m0+row)*KA + k0 + cc*8], (char*)As + (size_t)u0*16);
        } else {
          const int v2 = u0 - 512 + lane;
          const int n = v2 >> 2, cc = v2 & 3;
          load_lds16(&W[(size_t)(n0+n)*KA + k0 + cc*8], (char*)Ws + (size_t)(u0-512)*16);
        }
      }
    }
    __syncthreads();   // compiler drains vmcnt before barrier
    short8 a0 = *(const short8*)&As[(c*128 + w*32 + r16)*8];
    short8 a1 = *(const short8*)&As[(c*128 + w*32 + 16 + r16)*8];
    #pragma unroll
    for (int nf = 0; nf < NF; ++nf) {
      short8 bfr = *(const short8*)&Ws[((nf*16 + r16)*4 + c)*8];
      acc[0][nf] = __builtin_amdgcn_mfma_f32_16x16x32_bf16(a0, bfr, acc[0][nf], 0, 0, 0);
      acc[1][nf] = __builtin_amdgcn_mfma_f32_16x16x32_bf16(a1, bfr, acc[1][nf], 0, 0, 0);
    }
    __syncthreads();
  }
  // epilogue: C/D frag mapping col=lane&15, row=(lane>>4)*4+r
  const int rg = lane >> 4;
  #pragma unroll
  for (int mf = 0; mf < 2; ++mf) {
    #pragma unroll
    for (int nf = 0; nf < NF; ++nf) {
      const int colp = n0 + nf*16 + r16;
      const float bs = bias[colp];
      #pragma unroll
      for (int r = 0; r < 4; ++r) {
        const int row = m0 + w*32 + mf*16 + rg*4 + r;
        float val = acc[mf][nf][r] + bs;
        if (ACT == 1) val = sigf(val);
        else if (ACT == 2) val = expf(val);
        if (OUTMODE == 0) {
          if (colp < Nreal) ((float*)C)[(size_t)row*Nstride + colp] = val;
        } else {
          ((unsigned short*)C)[(size_t)row*Nstride + colp] = f2bf(val);
        }
      }
    }
  }
}

// =====================================================================
// Persistent bidirectional LSTM scan — MFMA recurrence.
// grid (128, 2): 8 batch rows/block, blockIdx.y = direction. 256 thr = 4 waves.
// B-frags (whh) live in VGPRs for all 50 steps; per step: 4 ds_read A-frags +
// 28 MFMA + gate phase. Static LDS 19 KB (was 118 KB -> 1 blk/CU, LDS-bound).
// =====================================================================
__global__ __launch_bounds__(256) void k_scan(
    const unsigned short* __restrict__ gx,     // [B*L][800] bf16: fwd [0,400), bwd [400,800)
    const unsigned short* __restrict__ whhpk,  // [2][448][128] bf16
    unsigned short* __restrict__ hout)         // [B*L][224] bf16
{
  __shared__ __attribute__((aligned(16))) unsigned short h_s[16][136]; // rows 8..15, cols>=100 stay 0; stride 136 kills A-read bank conflicts
  __shared__ float g_s[8][448];
  const int dir = blockIdx.y;
  const int b0 = blockIdx.x * 8;
  const int tid = threadIdx.x;
  const int lane = tid & 63, w = tid >> 6;
  const int r16 = lane & 15, c = lane >> 4;

  // ---- load B fragments (weights) once into VGPRs ----
  short8 bfr[7][4];
  {
    const unsigned short* wb = whhpk + (size_t)dir*448*128;
    #pragma unroll
    for (int nf = 0; nf < 7; ++nf)
      #pragma unroll
      for (int ks = 0; ks < 4; ++ks)
        bfr[nf][ks] = *(const short8*)&wb[(size_t)(w*112 + nf*16 + r16)*128 + ks*32 + c*8];
  }
  for (int idx = tid; idx < 16*136; idx += 256) ((unsigned short*)h_s)[idx] = 0;
  float cst[4] = {0.f,0.f,0.f,0.f};
  const int kh = tid % 100;
  const int r0 = tid / 100;          // 0 or 1 for active threads
  const bool pbact = (tid < 200);
  __syncthreads();

  for (int t = 0; t < L_; ++t) {
    const int tp = dir ? (L_-1-t) : t;
    // ---- phase A: g_mm = h @ whh^T via MFMA ----
    f32x4 acc[7];
    #pragma unroll
    for (int nf = 0; nf < 7; ++nf) acc[nf] = (f32x4){0.f,0.f,0.f,0.f};
    short8 afr[4];
    #pragma unroll
    for (int ks = 0; ks < 4; ++ks)
      afr[ks] = *(const short8*)&h_s[r16][ks*32 + c*8];
    #pragma unroll
    for (int ks = 0; ks < 4; ++ks)
      #pragma unroll
      for (int nf = 0; nf < 7; ++nf)
        acc[nf] = __builtin_amdgcn_mfma_f32_16x16x32_bf16(afr[ks], bfr[nf][ks], acc[nf], 0, 0, 0);
    // prefetch gx gates for phase B (overlaps MFMA + barrier)
    unsigned short gxr[4][4];
    if (pbact) {
      #pragma unroll
      for (int i = 0; i < 4; ++i) {
        const int row = r0 + 2*i;
        const size_t gbase = ((size_t)(b0+row)*L_ + tp)*800 + (size_t)dir*400 + kh;
        #pragma unroll
        for (int g = 0; g < 4; ++g) gxr[i][g] = gx[gbase + 100*g];
      }
    }
    // write C frags (rows < 8): col=lane&15, row=(lane>>4)*4+r
    if (c < 2) {
      #pragma unroll
      for (int nf = 0; nf < 7; ++nf) {
        const int col = w*112 + nf*16 + r16;
        #pragma unroll
        for (int r = 0; r < 4; ++r)
          g_s[c*4 + r][col] = acc[nf][r];
      }
    }
    __syncthreads();
    // ---- phase B: gates, c/h update ----
    if (pbact) {
      #pragma unroll
      for (int i = 0; i < 4; ++i) {
        const int row = r0 + 2*i;
        float gi = g_s[row][kh]       + bf2f(gxr[i][0]);
        float gf = g_s[row][kh + 100] + bf2f(gxr[i][1]);
        float gg = g_s[row][kh + 200] + bf2f(gxr[i][2]);
        float go = g_s[row][kh + 300] + bf2f(gxr[i][3]);
        float cn = sigf(gf)*cst[i] + sigf(gi)*tanhf(gg);
        cst[i] = cn;
        float hn = sigf(go)*tanhf(cn);
        unsigned short hb16 = f2bf(hn);
        h_s[row][kh] = hb16;
        hout[((size_t)(b0+row)*L_ + tp)*224 + dir*H_ + kh] = hb16;
      }
    }
    if (dir == 0 && tid < 192) {
      int r = tid / 24, p = tid - (tid/24)*24;
      hout[((size_t)(b0+r)*L_ + tp)*224 + 200 + p] = 0;
    }
    __syncthreads();
  }
}

// =====================================================================
// AFT attention: one block per batch element, fp32 in/out
// dynamic LDS = 40000 + 40000 + 11200 = 91200 B
// =====================================================================
__global__ __launch_bounds__(256) void k_attn(
    const float* __restrict__ sq, const float* __restrict__ ek, const float* __restrict__ v,
    const float* __restrict__ pos_bias, float* __restrict__ att)
{
  extern __shared__ char smem[];
  float* eks = (float*)smem;          // [50][200]
  float* evs = eks + L_*DH_;          // [50][200]
  float* wpT = evs + L_*DH_;          // [50][56]
  const int b = blockIdx.x, tid = threadIdx.x;
  const size_t base = (size_t)b*L_*DH_;
  for (int idx = tid; idx < L_*DH_; idx += 256) {
    float e = ek[base + idx];
    eks[idx] = e;
    evs[idx] = e * v[base + idx];
  }
  for (int idx = tid; idx < 50*56; idx += 256) {
    int j = idx / 56, i = idx - (idx/56)*56;
    wpT[idx] = (i < L_) ? expf(pos_bias[i*L_ + j]) : 0.f;
  }
  __syncthreads();
  if (tid < 175) {
    const int ioct = tid / 25, doct = tid - (tid/25)*25;
    const int i0 = ioct*8, d0 = doct*8;
    float num[8][8], den[8][8];
    #pragma unroll
    for (int i = 0; i < 8; ++i)
      #pragma unroll
      for (int j = 0; j < 8; ++j) { num[i][j] = 0.f; den[i][j] = 0.f; }
    for (int j = 0; j < L_; ++j) {
      float wv8[8], ee8[8], ev8[8];
      *(float4*)&wv8[0] = *(const float4*)&wpT[j*56 + i0];
      *(float4*)&wv8[4] = *(const float4*)&wpT[j*56 + i0 + 4];
      *(float4*)&ee8[0] = *(const float4*)&eks[j*DH_ + d0];
      *(float4*)&ee8[4] = *(const float4*)&eks[j*DH_ + d0 + 4];
      *(float4*)&ev8[0] = *(const float4*)&evs[j*DH_ + d0];
      *(float4*)&ev8[4] = *(const float4*)&evs[j*DH_ + d0 + 4];
      #pragma unroll
      for (int ii = 0; ii < 8; ++ii)
        #pragma unroll
        for (int dd = 0; dd < 8; ++dd) {
          num[ii][dd] = fmaf(wv8[ii], ev8[dd], num[ii][dd]);
          den[ii][dd] = fmaf(wv8[ii], ee8[dd], den[ii][dd]);
        }
    }
    for (int ii = 0; ii < 8; ++ii) {
      int i = i0 + ii;
      if (i >= L_) break;
      #pragma unroll
      for (int d4 = 0; d4 < 2; ++d4) {
        int d = d0 + d4*4;
        float4 s4 = *(const float4*)&sq[base + (size_t)i*DH_ + d];
        float4 o;
        o.x = s4.x * num[ii][d4*4+0] / den[ii][d4*4+0];
        o.y = s4.y * num[ii][d4*4+1] / den[ii][d4*4+1];
        o.z = s4.z * num[ii][d4*4+2] / den[ii][d4*4+2];
        o.w = s4.w * num[ii][d4*4+3] / den[ii][d4*4+3];
        *(float4*)&att[base + (size_t)i*DH_ + d] = o;
      }
    }
  }
}

// =====================================================================
// dense1 split-K (fp32)
// =====================================================================
__global__ __launch_bounds__(256) void k_dense1(
    const float* __restrict__ att, const float* __restrict__ dw1,
    float* __restrict__ part)
{
  __shared__ float fs[16][33];
  __shared__ float wsd[32][132];
  const int b0 = blockIdx.x*16;
  const int ks = blockIdx.y*1250;
  const int tid = threadIdx.x;
  const int og = tid & 15, bb = tid >> 4;
  float acc[8];
  #pragma unroll
  for (int u = 0; u < 8; ++u) acc[u] = 0.f;

  for (int k0 = ks; k0 < ks+1250; k0 += 32) {
    const int krem = (ks+1250-k0 < 32) ? (ks+1250-k0) : 32;
    {
      int idx = tid;
      #pragma unroll
      for (int it = 0; it < 2; ++it, idx += 256) {
        int bbs = idx >> 5, kk = idx & 31;
        fs[bbs][kk] = (kk < krem) ? att[(size_t)(b0+bbs)*KD_ + k0+kk] : 0.f;
      }
    }
    #pragma unroll
    for (int it = 0; it < 16; ++it) {
      int idx = tid + it*256;
      int o = idx & 127, kk = idx >> 7;
      wsd[kk][o] = (kk < krem) ? dw1[(size_t)o*KD_ + k0+kk] : 0.f;
    }
    __syncthreads();
    #pragma unroll
    for (int kk = 0; kk < 32; ++kk) {
      float a = fs[bb][kk];
      float w8[8];
      *(float4*)&w8[0] = *(const float4*)&wsd[kk][og*8];
      *(float4*)&w8[4] = *(const float4*)&wsd[kk][og*8+4];
      #pragma unroll
      for (int u = 0; u < 8; ++u) acc[u] = fmaf(a, w8[u], acc[u]);
    }
    __syncthreads();
  }
  float* pp = &part[((size_t)blockIdx.y*B_ + b0 + bb)*NHID_ + og*8];
  *(float4*)&pp[0] = make_float4(acc[0],acc[1],acc[2],acc[3]);
  *(float4*)&pp[4] = make_float4(acc[4],acc[5],acc[6],acc[7]);
}

// =====================================================================
// dense2
// =====================================================================
__global__ __launch_bounds__(128) void k_dense2(
    const float* __restrict__ part, const float* __restrict__ db1,
    const float* __restrict__ dw2, const float* __restrict__ db2,
    float* __restrict__ out)
{
  __shared__ float hid[NHID_];
  const int b = blockIdx.x, o = threadIdx.x;
  float s = db1[o];
  #pragma unroll
  for (int sl = 0; sl < 8; ++sl) s += part[((size_t)sl*B_ + b)*NHID_ + o];
  hid[o] = fmaxf(s, 0.f);
  __syncthreads();
  if (o < 5) {
    float acc = db2[o];
    for (int j = 0; j < NHID_; ++j) acc = fmaf(hid[j], dw2[o*NHID_ + j], acc);
    out[b*5 + o] = sigf(acc);
  }
}

// =====================================================================
extern "C" void kernel_launch(void* const* d_in, const int* in_sizes, int n_in,
                              void* d_out, int out_size, void* d_ws, size_t ws_size,
                              hipStream_t stream)
{
  const int*   x     = (const int*)  d_in[0];
  const float* emb1  = (const float*)d_in[1];
  const float* emb2  = (const float*)d_in[2];
  const float* cw2   = (const float*)d_in[3];
  const float* cb2   = (const float*)d_in[4];
  const float* cw3   = (const float*)d_in[5];
  const float* cb3   = (const float*)d_in[6];
  const float* cw8   = (const float*)d_in[7];
  const float* cb8   = (const float*)d_in[8];
  const float* wih_f = (const float*)d_in[9];
  const float* whh_f = (const float*)d_in[10];
  const float* bih_f = (const float*)d_in[11];
  const float* bhh_f = (const float*)d_in[12];
  const float* wih_b = (const float*)d_in[13];
  const float* whh_b = (const float*)d_in[14];
  const float* bih_b = (const float*)d_in[15];
  const float* bhh_b = (const float*)d_in[16];
  const float* wq    = (const float*)d_in[17];
  const float* bq    = (const float*)d_in[18];
  const float* wk    = (const float*)d_in[19];
  const float* bk    = (const float*)d_in[20];
  const float* wv    = (const float*)d_in[21];
  const float* bv    = (const float*)d_in[22];
  const float* pos_bias = (const float*)d_in[23];
  const float* dw1   = (const float*)d_in[24];
  const float* db1   = (const float*)d_in[25];
  const float* dw2   = (const float*)d_in[26];
  const float* db2   = (const float*)d_in[27];
  (void)in_sizes; (void)n_in; (void)out_size;

  // ---- workspace layout (bytes, 256-aligned) ----
  char* base = (char*)d_ws;
  size_t off = 0;
  auto alloc = [&](size_t bytes) -> char* {
    char* p = base + off;
    off = (off + bytes + 255) & ~(size_t)255;
    return p;
  };
  unsigned short* seqb  = (unsigned short*)alloc(51200UL*256*2);   // 26.2 MB
  unsigned short* gxb   = (unsigned short*)alloc(51200UL*800*2);   // 81.9 MB
  unsigned short* hb    = (unsigned short*)alloc(51200UL*224*2);   // 22.9 MB
  float*          sqb   = (float*)alloc(51200UL*200*4);            // 41.0 MB
  float*          ekb   = (float*)alloc(51200UL*200*4);            // 41.0 MB
  float*          vb    = (float*)alloc(51200UL*200*4);            // 41.0 MB
  unsigned short* wihp  = (unsigned short*)alloc(204800UL*2);
  float*          bihp  = (float*)alloc(800UL*4);
  unsigned short* wqkvp = (unsigned short*)alloc(150528UL*2);
  float*          bqkvp = (float*)alloc(672UL*4);
  unsigned short* whhpk = (unsigned short*)alloc(114688UL*2);
  if (off > ws_size) return;                 // ~255 MB total
  float* attb = (float*)gxb;                 // overlay: gx dead after scan
  float* part = (float*)seqb;                // overlay: seq dead after gx GEMM

  hipFuncSetAttribute(reinterpret_cast<const void*>(k_attn),
                      hipFuncAttributeMaxDynamicSharedMemorySize, 91200);

  k_pack<<<dim3(1842), 256, 0, stream>>>(wih_f, bih_f, bhh_f, wih_b, bih_b, bhh_b,
                                         whh_f, whh_b, wq, bq, wk, bk, wv, bv,
                                         wihp, bihp, wqkvp, bqkvp, whhpk);
  k_embconv<<<dim3(1024), 256, 0, stream>>>(x, emb1, emb2, cw2, cb2, cw3, cb3, cw8, cb8, seqb);
  // gx = seq @ [wih_f|wih_b]^T + biases  -> bf16 (M=51200, N=800, K=256)
  k_gemm_mfma<5, 8, 0, 1><<<dim3(400, 10), 256, 0, stream>>>(seqb, wihp, bihp, gxb, 800, 800);
  k_scan<<<dim3(128, 2), 256, 0, stream>>>(gxb, whhpk, hb);
  // q/k/v GEMMs (M=51200, N=200 pad 224, K=224), epilogue sigmoid/exp/none
  k_gemm_mfma<7, 7, 1, 0><<<dim3(400, 2), 256, 0, stream>>>(hb, wqkvp,          bqkvp,       sqb, 200, 200);
  k_gemm_mfma<7, 7, 2, 0><<<dim3(400, 2), 256, 0, stream>>>(hb, wqkvp + 50176,  bqkvp + 224, ekb, 200, 200);
  k_gemm_mfma<7, 7, 0, 0><<<dim3(400, 2), 256, 0, stream>>>(hb, wqkvp + 100352, bqkvp + 448, vb,  200, 200);
  k_attn<<<dim3(1024), 256, 91200, stream>>>(sqb, ekb, vb, pos_bias, attb);
  k_dense1<<<dim3(64, 8), 256, 0, stream>>>(attb, dw1, part);
  k_dense2<<<dim3(1024), 128, 0, stream>>>(part, db1, dw2, db2, (float*)d_out);
}

// Round 10
// 546.748 us; speedup vs baseline: 6.3057x; 1.5351x over previous
//
#include <hip/hip_runtime.h>
#include <cstdint>
#include <cstddef>

// ---- model dims ----
#define B_    1024
#define L_    50
#define EMB_  63
#define CD_   60
#define H_    100
#define G4_   400     // 4*H
#define DH_   200     // 2*H
#define NHID_ 128
#define KD_   10000   // L_*DH_
#define KDP_  10240   // padded K for dense1 MFMA
#define NSPL_ 16      // dense1 split-K slices (640 K each)

typedef __attribute__((ext_vector_type(8))) short short8;
typedef __attribute__((ext_vector_type(4))) float f32x4;

// ---------- helpers ----------
__device__ __forceinline__ float sigf(float x){ return 1.f/(1.f+expf(-x)); }
__device__ __forceinline__ unsigned short f2bf(float f){
  unsigned int x = __float_as_uint(f);
  unsigned int r = x + 0x7fffu + ((x>>16)&1u);   // RNE
  return (unsigned short)(r>>16);
}
__device__ __forceinline__ float bf2f(unsigned short u){
  return __uint_as_float(((unsigned int)u)<<16);
}
__device__ __forceinline__ void load_lds16(const void* g, void* l){
  // 16B per lane, LDS dst = wave-uniform base + lane*16
  __builtin_amdgcn_global_load_lds((const __attribute__((address_space(1))) void*)g,
                                   (__attribute__((address_space(3))) void*)l, 16, 0, 0);
}

// =====================================================================
// K0: pack weights to bf16 padded layouts
//  wihp  [2][400][256] bf16 (K 243->256 zero pad)
//  bihp  [800] = bih+bhh (fwd | bwd)
//  wqkvp [3][224][224] bf16 (N 200->224 zero rows, K 200->224 zero cols)
//  bqkvp [3][224]
//  whhpk [2][448][128] bf16 (N 400->448 zero rows, K 100->128 zero cols)
//  dw1p  [128][10240] bf16 (K 10000->10240 zero pad)
// =====================================================================
__global__ __launch_bounds__(256) void k_pack(
    const float* __restrict__ wih_f, const float* __restrict__ bih_f, const float* __restrict__ bhh_f,
    const float* __restrict__ wih_b, const float* __restrict__ bih_b, const float* __restrict__ bhh_b,
    const float* __restrict__ whh_f, const float* __restrict__ whh_b,
    const float* __restrict__ wq, const float* __restrict__ bq,
    const float* __restrict__ wk, const float* __restrict__ bk,
    const float* __restrict__ wv, const float* __restrict__ bv,
    const float* __restrict__ dw1,
    unsigned short* __restrict__ wihp, float* __restrict__ bihp,
    unsigned short* __restrict__ wqkvp, float* __restrict__ bqkvp,
    unsigned short* __restrict__ whhpk, unsigned short* __restrict__ dw1p)
{
  int i = blockIdx.x*256 + threadIdx.x;
  if (i < 204800) {
    int d = i / 102400, rem = i % 102400, r = rem >> 8, k = rem & 255;
    const float* src = d ? wih_b : wih_f;
    wihp[i] = f2bf((k < 243) ? src[r*243 + k] : 0.f);
  } else if ((i -= 204800) < 800) {
    bihp[i] = (i < 400) ? (bih_f[i] + bhh_f[i]) : (bih_b[i-400] + bhh_b[i-400]);
  } else if ((i -= 800) < 150528) {
    int s = i / 50176, rem = i % 50176, n = rem / 224, k = rem % 224;
    const float* w = (s==0) ? wq : (s==1) ? wk : wv;
    wqkvp[i] = f2bf((n < 200 && k < 200) ? w[n*200 + k] : 0.f);
  } else if ((i -= 150528) < 672) {
    int s = i / 224, n = i % 224;
    const float* bb = (s==0) ? bq : (s==1) ? bk : bv;
    bqkvp[i] = (n < 200) ? bb[n] : 0.f;
  } else if ((i -= 672) < 114688) {
    int d = i / 57344, rem = i % 57344, n = rem >> 7, k = rem & 127;
    const float* src = d ? whh_b : whh_f;
    whhpk[i] = f2bf((n < 400 && k < 100) ? src[n*100 + k] : 0.f);
  } else if ((i -= 114688) < 1310720) {
    int n = i / KDP_, k = i % KDP_;
    dw1p[i] = f2bf((k < KD_) ? dw1[(size_t)n*KD_ + k] : 0.f);
  }
}

// =====================================================================
// K1: embedding + 3 conv branches + relu + maxpool + pad -> seq bf16 [B*L][256]
// ys transposed to [49][65] (odd stride -> bank spread); o-block=2 halves
// x0s LDS re-reads.
// =====================================================================
template<int KH>
__device__ __forceinline__ void conv_branch(
    const float (&x0s)[EMB_][64], float (&ys)[49][65],
    const float* __restrict__ w, const float* __restrict__ cb,
    unsigned short* __restrict__ seq, int b, int co, int tid)
{
  const int Lc = 51 - KH;
  const int Lp = Lc - 2;
  const int nt8 = (Lc + 7) >> 3;
  const int ntask = 30 * nt8;          // 2 output channels per task
  for (int task = tid; task < ntask; task += 256) {
    int o2 = task / nt8, tc = (task % nt8) << 3;
    const int o0 = o2*2;
    float acc[2][8];
    {
      float b0v = cb[o0], b1v = cb[o0+1];
      #pragma unroll
      for (int j = 0; j < 8; ++j) { acc[0][j] = b0v; acc[1][j] = b1v; }
    }
    for (int c = 0; c < EMB_; ++c) {
      float xw[16];
      const float* xr = &x0s[c][tc];
      *(float4*)&xw[0]  = *(const float4*)&xr[0];
      *(float4*)&xw[4]  = *(const float4*)&xr[4];
      *(float4*)&xw[8]  = *(const float4*)&xr[8];
      *(float4*)&xw[12] = *(const float4*)&xr[12];
      const float* wr0 = &w[(size_t)(o0*EMB_ + c)*KH];
      const float* wr1 = &w[(size_t)((o0+1)*EMB_ + c)*KH];
      #pragma unroll
      for (int tau = 0; tau < KH; ++tau) {
        float w0 = wr0[tau], w1 = wr1[tau];
        #pragma unroll
        for (int j = 0; j < 8; ++j) {
          acc[0][j] = fmaf(xw[tau+j], w0, acc[0][j]);
          acc[1][j] = fmaf(xw[tau+j], w1, acc[1][j]);
        }
      }
    }
    #pragma unroll
    for (int j = 0; j < 8; ++j) {
      int t = tc + j;
      if (t < Lc) {
        ys[t][o0]   = fmaxf(acc[0][j], 0.f);
        ys[t][o0+1] = fmaxf(acc[1][j], 0.f);
      }
    }
  }
  __syncthreads();
  for (int idx = tid; idx < L_*CD_; idx += 256) {
    int l = idx / CD_, o = idx - (idx/CD_)*CD_;
    float vm = 0.f;
    if (l < Lp) {
      int lo = (l-1 < 0) ? 0 : l-1;
      int hi = (l+3 >= Lc) ? Lc-1 : l+3;
      for (int t = lo; t <= hi; ++t) vm = fmaxf(vm, ys[t][o]);
    }
    seq[((size_t)b*L_ + l)*256 + co + o] = f2bf(vm);
  }
  __syncthreads();
}

__global__ __launch_bounds__(256) void k_embconv(
    const int* __restrict__ x, const float* __restrict__ emb1, const float* __restrict__ emb2,
    const float* __restrict__ cw2, const float* __restrict__ cb2,
    const float* __restrict__ cw3, const float* __restrict__ cb3,
    const float* __restrict__ cw8, const float* __restrict__ cb8,
    unsigned short* __restrict__ seq)
{
  __shared__ float x0s[EMB_][64];
  __shared__ float ys[49][65];
  __shared__ int   xs[L_];
  const int b = blockIdx.x, tid = threadIdx.x;
  if (tid < L_) xs[tid] = x[b*L_ + tid];
  __syncthreads();
  for (int idx = tid; idx < EMB_*64; idx += 256) {
    int c = idx >> 6, l = idx & 63;
    float v = 0.f;
    if (l < L_) { int e = xs[l]; v = (c < 21) ? emb1[e*21 + c] : emb2[e*42 + (c-21)]; }
    x0s[c][l] = v;
  }
  __syncthreads();
  // x0 channels [0,63) + K-pad cols [243,256)
  for (int idx = tid; idx < L_*EMB_; idx += 256) {
    int l = idx / EMB_, c = idx - (idx/EMB_)*EMB_;
    seq[((size_t)b*L_ + l)*256 + c] = f2bf(x0s[c][l]);
  }
  for (int idx = tid; idx < L_*13; idx += 256) {
    int l = idx / 13, p = idx - (idx/13)*13;
    seq[((size_t)b*L_ + l)*256 + 243 + p] = 0;
  }
  __syncthreads();
  conv_branch<2>(x0s, ys, cw2, cb2, seq, b, EMB_,          tid);
  conv_branch<3>(x0s, ys, cw3, cb3, seq, b, EMB_ + CD_,    tid);
  conv_branch<8>(x0s, ys, cw8, cb8, seq, b, EMB_ + 2*CD_,  tid);
}

// =====================================================================
// bf16 MFMA GEMM: C(M, N) = act(A(M,KA) @ W(N,KA)^T + bias)
// BM=128, BN=NF*16, BK=32. 256 thr = 4 waves, each wave: 32 rows x BN cols.
// OUTMODE 0: fp32 store, mask col<Nreal; 1: bf16 store unmasked.
// ACT 0 none, 1 sigmoid, 2 exp
// =====================================================================
template<int NF, int KSTEPS, int ACT, int OUTMODE>
__global__ __launch_bounds__(256) void k_gemm_mfma(
    const unsigned short* __restrict__ A,
    const unsigned short* __restrict__ W,
    const float* __restrict__ bias,
    void* __restrict__ C, int Nstride, int Nreal)
{
  constexpr int BN = NF*16;
  constexpr int KA = KSTEPS*32;
  constexpr int TU = 512 + BN*4;       // 16B staging units per K-tile
  __shared__ __attribute__((aligned(16))) unsigned short As[512*8];
  __shared__ __attribute__((aligned(16))) unsigned short Ws[BN*32];
  const int tid = threadIdx.x;
  const int lane = tid & 63, w = tid >> 6;
  const int m0 = blockIdx.x*128, n0 = blockIdx.y*BN;
  const int c = lane >> 4, r16 = lane & 15;
  f32x4 acc[2][NF];
  #pragma unroll
  for (int i = 0; i < 2; ++i)
    #pragma unroll
    for (int j = 0; j < NF; ++j) acc[i][j] = (f32x4){0.f,0.f,0.f,0.f};

  for (int ks = 0; ks < KSTEPS; ++ks) {
    const int k0 = ks*32;
    #pragma unroll
    for (int it = 0; it*256 < TU; ++it) {
      const int u0 = it*256 + w*64;           // wave-uniform
      if (u0 < TU) {
        if (u0 < 512) {
          const int u = u0 + lane;
          const int cc = u >> 7, row = u & 127;
          load_lds16(&A[(size_t)(m0+row)*KA + k0 + cc*8], (char*)As + (size_t)u0*16);
        } else {
          const int v2 = u0 - 512 + lane;
          const int n = v2 >> 2, cc = v2 & 3;
          load_lds16(&W[(size_t)(n0+n)*KA + k0 + cc*8], (char*)Ws + (size_t)(u0-512)*16);
        }
      }
    }
    __syncthreads();   // compiler drains vmcnt before barrier
    short8 a0 = *(const short8*)&As[(c*128 + w*32 + r16)*8];
    short8 a1 = *(const short8*)&As[(c*128 + w*32 + 16 + r16)*8];
    #pragma unroll
    for (int nf = 0; nf < NF; ++nf) {
      short8 bfr = *(const short8*)&Ws[((nf*16 + r16)*4 + c)*8];
      acc[0][nf] = __builtin_amdgcn_mfma_f32_16x16x32_bf16(a0, bfr, acc[0][nf], 0, 0, 0);
      acc[1][nf] = __builtin_amdgcn_mfma_f32_16x16x32_bf16(a1, bfr, acc[1][nf], 0, 0, 0);
    }
    __syncthreads();
  }
  // epilogue: C/D frag mapping col=lane&15, row=(lane>>4)*4+r
  const int rg = lane >> 4;
  #pragma unroll
  for (int mf = 0; mf < 2; ++mf) {
    #pragma unroll
    for (int nf = 0; nf < NF; ++nf) {
      const int colp = n0 + nf*16 + r16;
      const float bs = bias[colp];
      #pragma unroll
      for (int r = 0; r < 4; ++r) {
        const int row = m0 + w*32 + mf*16 + rg*4 + r;
        float val = acc[mf][nf][r] + bs;
        if (ACT == 1) val = sigf(val);
        else if (ACT == 2) val = expf(val);
        if (OUTMODE == 0) {
          if (colp < Nreal) ((float*)C)[(size_t)row*Nstride + colp] = val;
        } else {
          ((unsigned short*)C)[(size_t)row*Nstride + colp] = f2bf(val);
        }
      }
    }
  }
}

// =====================================================================
// Persistent bidirectional LSTM scan — MFMA recurrence.
// grid (128, 2): 8 batch rows/block, blockIdx.y = direction. 256 thr = 4 waves.
// =====================================================================
__global__ __launch_bounds__(256) void k_scan(
    const unsigned short* __restrict__ gx,     // [B*L][800] bf16: fwd [0,400), bwd [400,800)
    const unsigned short* __restrict__ whhpk,  // [2][448][128] bf16
    unsigned short* __restrict__ hout)         // [B*L][224] bf16
{
  __shared__ __attribute__((aligned(16))) unsigned short h_s[16][136];
  __shared__ float g_s[8][448];
  const int dir = blockIdx.y;
  const int b0 = blockIdx.x * 8;
  const int tid = threadIdx.x;
  const int lane = tid & 63, w = tid >> 6;
  const int r16 = lane & 15, c = lane >> 4;

  // ---- load B fragments (weights) once into VGPRs ----
  short8 bfr[7][4];
  {
    const unsigned short* wb = whhpk + (size_t)dir*448*128;
    #pragma unroll
    for (int nf = 0; nf < 7; ++nf)
      #pragma unroll
      for (int ks = 0; ks < 4; ++ks)
        bfr[nf][ks] = *(const short8*)&wb[(size_t)(w*112 + nf*16 + r16)*128 + ks*32 + c*8];
  }
  for (int idx = tid; idx < 16*136; idx += 256) ((unsigned short*)h_s)[idx] = 0;
  float cst[4] = {0.f,0.f,0.f,0.f};
  const int kh = tid % 100;
  const int r0 = tid / 100;
  const bool pbact = (tid < 200);
  __syncthreads();

  for (int t = 0; t < L_; ++t) {
    const int tp = dir ? (L_-1-t) : t;
    // ---- phase A: g_mm = h @ whh^T via MFMA ----
    f32x4 acc[7];
    #pragma unroll
    for (int nf = 0; nf < 7; ++nf) acc[nf] = (f32x4){0.f,0.f,0.f,0.f};
    short8 afr[4];
    #pragma unroll
    for (int ks = 0; ks < 4; ++ks)
      afr[ks] = *(const short8*)&h_s[r16][ks*32 + c*8];
    #pragma unroll
    for (int ks = 0; ks < 4; ++ks)
      #pragma unroll
      for (int nf = 0; nf < 7; ++nf)
        acc[nf] = __builtin_amdgcn_mfma_f32_16x16x32_bf16(afr[ks], bfr[nf][ks], acc[nf], 0, 0, 0);
    // prefetch gx gates for phase B
    unsigned short gxr[4][4];
    if (pbact) {
      #pragma unroll
      for (int i = 0; i < 4; ++i) {
        const int row = r0 + 2*i;
        const size_t gbase = ((size_t)(b0+row)*L_ + tp)*800 + (size_t)dir*400 + kh;
        #pragma unroll
        for (int g = 0; g < 4; ++g) gxr[i][g] = gx[gbase + 100*g];
      }
    }
    // write C frags (rows < 8)
    if (c < 2) {
      #pragma unroll
      for (int nf = 0; nf < 7; ++nf) {
        const int col = w*112 + nf*16 + r16;
        #pragma unroll
        for (int r = 0; r < 4; ++r)
          g_s[c*4 + r][col] = acc[nf][r];
      }
    }
    __syncthreads();
    // ---- phase B: gates, c/h update ----
    if (pbact) {
      #pragma unroll
      for (int i = 0; i < 4; ++i) {
        const int row = r0 + 2*i;
        float gi = g_s[row][kh]       + bf2f(gxr[i][0]);
        float gf = g_s[row][kh + 100] + bf2f(gxr[i][1]);
        float gg = g_s[row][kh + 200] + bf2f(gxr[i][2]);
        float go = g_s[row][kh + 300] + bf2f(gxr[i][3]);
        float cn = sigf(gf)*cst[i] + sigf(gi)*tanhf(gg);
        cst[i] = cn;
        float hn = sigf(go)*tanhf(cn);
        unsigned short hb16 = f2bf(hn);
        h_s[row][kh] = hb16;
        hout[((size_t)(b0+row)*L_ + tp)*224 + dir*H_ + kh] = hb16;
      }
    }
    if (dir == 0 && tid < 192) {
      int r = tid / 24, p = tid - (tid/24)*24;
      hout[((size_t)(b0+r)*L_ + tp)*224 + 200 + p] = 0;
    }
    __syncthreads();
  }
}

// =====================================================================
// AFT attention: one block per batch element; ek/ek*v staged bf16 in LDS
// (51.2 KB -> 3 blocks/CU). Output att bf16 [1024][10240] (pad-zeroed).
// =====================================================================
__global__ __launch_bounds__(256) void k_attn(
    const float* __restrict__ sq, const float* __restrict__ ek, const float* __restrict__ v,
    const float* __restrict__ pos_bias, unsigned short* __restrict__ att)
{
  extern __shared__ char smem[];
  unsigned short* eks = (unsigned short*)smem;          // [50][200] bf16
  unsigned short* evs = eks + L_*DH_;                   // [50][200] bf16
  float* wpT = (float*)(smem + 40000);                  // [50][56] fp32
  const int b = blockIdx.x, tid = threadIdx.x;
  const size_t base = (size_t)b*KD_;
  const size_t obase = (size_t)b*KDP_;
  for (int idx = tid; idx < L_*DH_; idx += 256) {
    float e = ek[base + idx];
    eks[idx] = f2bf(e);
    evs[idx] = f2bf(e * v[base + idx]);
  }
  for (int idx = tid; idx < 50*56; idx += 256) {
    int j = idx / 56, i = idx - (idx/56)*56;
    wpT[idx] = (i < L_) ? expf(pos_bias[i*L_ + j]) : 0.f;
  }
  __syncthreads();
  if (tid < 175) {
    const int ioct = tid / 25, doct = tid - (tid/25)*25;
    const int i0 = ioct*8, d0 = doct*8;
    float num[8][8], den[8][8];
    #pragma unroll
    for (int i = 0; i < 8; ++i)
      #pragma unroll
      for (int j = 0; j < 8; ++j) { num[i][j] = 0.f; den[i][j] = 0.f; }
    for (int j = 0; j < L_; ++j) {
      float wv8[8], ee8[8], ev8[8];
      *(float4*)&wv8[0] = *(const float4*)&wpT[j*56 + i0];
      *(float4*)&wv8[4] = *(const float4*)&wpT[j*56 + i0 + 4];
      short8 ee = *(const short8*)&eks[j*DH_ + d0];
      short8 ev = *(const short8*)&evs[j*DH_ + d0];
      #pragma unroll
      for (int u = 0; u < 8; ++u) {
        ee8[u] = bf2f((unsigned short)ee[u]);
        ev8[u] = bf2f((unsigned short)ev[u]);
      }
      #pragma unroll
      for (int ii = 0; ii < 8; ++ii)
        #pragma unroll
        for (int dd = 0; dd < 8; ++dd) {
          num[ii][dd] = fmaf(wv8[ii], ev8[dd], num[ii][dd]);
          den[ii][dd] = fmaf(wv8[ii], ee8[dd], den[ii][dd]);
        }
    }
    for (int ii = 0; ii < 8; ++ii) {
      int i = i0 + ii;
      if (i >= L_) break;
      #pragma unroll
      for (int d4 = 0; d4 < 2; ++d4) {
        int d = d0 + d4*4;
        float4 s4 = *(const float4*)&sq[base + (size_t)i*DH_ + d];
        att[obase + (size_t)i*DH_ + d + 0] = f2bf(s4.x * num[ii][d4*4+0] / den[ii][d4*4+0]);
        att[obase + (size_t)i*DH_ + d + 1] = f2bf(s4.y * num[ii][d4*4+1] / den[ii][d4*4+1]);
        att[obase + (size_t)i*DH_ + d + 2] = f2bf(s4.z * num[ii][d4*4+2] / den[ii][d4*4+2]);
        att[obase + (size_t)i*DH_ + d + 3] = f2bf(s4.w * num[ii][d4*4+3] / den[ii][d4*4+3]);
      }
    }
  }
  // zero K-pad cols [10000,10240)
  for (int idx = tid; idx < KDP_ - KD_; idx += 256) att[obase + KD_ + idx] = 0;
}

// =====================================================================
// dense1 via bf16 MFMA, split-K.
// grid (8 m-blocks, 16 K-slices of 640). part[16][1024][128] fp32.
// =====================================================================
__global__ __launch_bounds__(256) void k_dense1m(
    const unsigned short* __restrict__ att,   // [1024][10240] bf16
    const unsigned short* __restrict__ dw1p,  // [128][10240] bf16
    float* __restrict__ part)
{
  __shared__ __attribute__((aligned(16))) unsigned short As[512*8];
  __shared__ __attribute__((aligned(16))) unsigned short Ws[128*32];
  const int tid = threadIdx.x;
  const int lane = tid & 63, w = tid >> 6;
  const int m0 = blockIdx.x*128;
  const int koff = blockIdx.y*640;
  const int c = lane >> 4, r16 = lane & 15;
  f32x4 acc[2][8];
  #pragma unroll
  for (int i = 0; i < 2; ++i)
    #pragma unroll
    for (int j = 0; j < 8; ++j) acc[i][j] = (f32x4){0.f,0.f,0.f,0.f};

  for (int ks = 0; ks < 20; ++ks) {
    const int k0 = koff + ks*32;
    #pragma unroll
    for (int it = 0; it < 4; ++it) {
      const int u0 = it*256 + w*64;
      if (u0 < 512) {
        const int u = u0 + lane;
        const int cc = u >> 7, row = u & 127;
        load_lds16(&att[(size_t)(m0+row)*KDP_ + k0 + cc*8], (char*)As + (size_t)u0*16);
      } else {
        const int v2 = u0 - 512 + lane;
        const int n = v2 >> 2, cc = v2 & 3;
        load_lds16(&dw1p[(size_t)n*KDP_ + k0 + cc*8], (char*)Ws + (size_t)(u0-512)*16);
      }
    }
    __syncthreads();
    short8 a0 = *(const short8*)&As[(c*128 + w*32 + r16)*8];
    short8 a1 = *(const short8*)&As[(c*128 + w*32 + 16 + r16)*8];
    #pragma unroll
    for (int nf = 0; nf < 8; ++nf) {
      short8 bfr = *(const short8*)&Ws[((nf*16 + r16)*4 + c)*8];
      acc[0][nf] = __builtin_amdgcn_mfma_f32_16x16x32_bf16(a0, bfr, acc[0][nf], 0, 0, 0);
      acc[1][nf] = __builtin_amdgcn_mfma_f32_16x16x32_bf16(a1, bfr, acc[1][nf], 0, 0, 0);
    }
    __syncthreads();
  }
  const int rg = lane >> 4;
  #pragma unroll
  for (int mf = 0; mf < 2; ++mf)
    #pragma unroll
    for (int nf = 0; nf < 8; ++nf) {
      const int col = nf*16 + r16;
      #pragma unroll
      for (int r = 0; r < 4; ++r) {
        const int row = m0 + w*32 + mf*16 + rg*4 + r;
        part[((size_t)blockIdx.y*B_ + row)*NHID_ + col] = acc[mf][nf][r];
      }
    }
}

// =====================================================================
// dense2: reduce 16 split-K partials + bias + relu, then 128->5 + sigmoid
// =====================================================================
__global__ __launch_bounds__(128) void k_dense2(
    const float* __restrict__ part, const float* __restrict__ db1,
    const float* __restrict__ dw2, const float* __restrict__ db2,
    float* __restrict__ out)
{
  __shared__ float hid[NHID_];
  const int b = blockIdx.x, o = threadIdx.x;
  float s = db1[o];
  #pragma unroll
  for (int sl = 0; sl < NSPL_; ++sl) s += part[((size_t)sl*B_ + b)*NHID_ + o];
  hid[o] = fmaxf(s, 0.f);
  __syncthreads();
  if (o < 5) {
    float acc = db2[o];
    for (int j = 0; j < NHID_; ++j) acc = fmaf(hid[j], dw2[o*NHID_ + j], acc);
    out[b*5 + o] = sigf(acc);
  }
}

// =====================================================================
extern "C" void kernel_launch(void* const* d_in, const int* in_sizes, int n_in,
                              void* d_out, int out_size, void* d_ws, size_t ws_size,
                              hipStream_t stream)
{
  const int*   x     = (const int*)  d_in[0];
  const float* emb1  = (const float*)d_in[1];
  const float* emb2  = (const float*)d_in[2];
  const float* cw2   = (const float*)d_in[3];
  const float* cb2   = (const float*)d_in[4];
  const float* cw3   = (const float*)d_in[5];
  const float* cb3   = (const float*)d_in[6];
  const float* cw8   = (const float*)d_in[7];
  const float* cb8   = (const float*)d_in[8];
  const float* wih_f = (const float*)d_in[9];
  const float* whh_f = (const float*)d_in[10];
  const float* bih_f = (const float*)d_in[11];
  const float* bhh_f = (const float*)d_in[12];
  const float* wih_b = (const float*)d_in[13];
  const float* whh_b = (const float*)d_in[14];
  const float* bih_b = (const float*)d_in[15];
  const float* bhh_b = (const float*)d_in[16];
  const float* wq    = (const float*)d_in[17];
  const float* bq    = (const float*)d_in[18];
  const float* wk    = (const float*)d_in[19];
  const float* bk    = (const float*)d_in[20];
  const float* wv    = (const float*)d_in[21];
  const float* bv    = (const float*)d_in[22];
  const float* pos_bias = (const float*)d_in[23];
  const float* dw1   = (const float*)d_in[24];
  const float* db1   = (const float*)d_in[25];
  const float* dw2   = (const float*)d_in[26];
  const float* db2   = (const float*)d_in[27];
  (void)in_sizes; (void)n_in; (void)out_size;

  // ---- workspace layout (bytes, 256-aligned) ----
  char* base = (char*)d_ws;
  size_t off = 0;
  auto alloc = [&](size_t bytes) -> char* {
    char* p = base + off;
    off = (off + bytes + 255) & ~(size_t)255;
    return p;
  };
  unsigned short* seqb  = (unsigned short*)alloc(51200UL*256*2);   // 26.2 MB
  unsigned short* gxb   = (unsigned short*)alloc(51200UL*800*2);   // 81.9 MB
  unsigned short* hb    = (unsigned short*)alloc(51200UL*224*2);   // 22.9 MB
  float*          sqb   = (float*)alloc(51200UL*200*4);            // 41.0 MB
  float*          ekb   = (float*)alloc(51200UL*200*4);            // 41.0 MB
  float*          vb    = (float*)alloc(51200UL*200*4);            // 41.0 MB
  unsigned short* wihp  = (unsigned short*)alloc(204800UL*2);
  float*          bihp  = (float*)alloc(800UL*4);
  unsigned short* wqkvp = (unsigned short*)alloc(150528UL*2);
  float*          bqkvp = (float*)alloc(672UL*4);
  unsigned short* whhpk = (unsigned short*)alloc(114688UL*2);
  unsigned short* dw1p  = (unsigned short*)alloc(1310720UL*2);     // 2.6 MB
  if (off > ws_size) return;                 // ~258 MB total
  unsigned short* attb = (unsigned short*)gxb; // overlay: gx dead after scan; bf16 [1024][10240] = 21 MB
  float* part = (float*)seqb;                  // overlay: seq dead after gx GEMM; [16][1024][128] = 8.4 MB

  hipFuncSetAttribute(reinterpret_cast<const void*>(k_attn),
                      hipFuncAttributeMaxDynamicSharedMemorySize, 51200);

  k_pack<<<dim3(6962), 256, 0, stream>>>(wih_f, bih_f, bhh_f, wih_b, bih_b, bhh_b,
                                         whh_f, whh_b, wq, bq, wk, bk, wv, bv, dw1,
                                         wihp, bihp, wqkvp, bqkvp, whhpk, dw1p);
  k_embconv<<<dim3(1024), 256, 0, stream>>>(x, emb1, emb2, cw2, cb2, cw3, cb3, cw8, cb8, seqb);
  // gx = seq @ [wih_f|wih_b]^T + biases  -> bf16 (M=51200, N=800, K=256)
  k_gemm_mfma<5, 8, 0, 1><<<dim3(400, 10), 256, 0, stream>>>(seqb, wihp, bihp, gxb, 800, 800);
  k_scan<<<dim3(128, 2), 256, 0, stream>>>(gxb, whhpk, hb);
  // q/k/v GEMMs (M=51200, N=200 pad 224, K=224), epilogue sigmoid/exp/none
  k_gemm_mfma<7, 7, 1, 0><<<dim3(400, 2), 256, 0, stream>>>(hb, wqkvp,          bqkvp,       sqb, 200, 200);
  k_gemm_mfma<7, 7, 2, 0><<<dim3(400, 2), 256, 0, stream>>>(hb, wqkvp + 50176,  bqkvp + 224, ekb, 200, 200);
  k_gemm_mfma<7, 7, 0, 0><<<dim3(400, 2), 256, 0, stream>>>(hb, wqkvp + 100352, bqkvp + 448, vb,  200, 200);
  k_attn<<<dim3(1024), 256, 51200, stream>>>(sqb, ekb, vb, pos_bias, attb);
  k_dense1m<<<dim3(8, NSPL_), 256, 0, stream>>>(attb, dw1p, part);
  k_dense2<<<dim3(1024), 128, 0, stream>>>(part, db1, dw2, db2, (float*)d_out);
}

// Round 11
// 486.707 us; speedup vs baseline: 7.0835x; 1.1234x over previous
//
#include <hip/hip_runtime.h>
#include <cstdint>
#include <cstddef>

// ---- model dims ----
#define B_    1024
#define L_    50
#define EMB_  63
#define CD_   60
#define H_    100
#define G4_   400     // 4*H
#define DH_   200     // 2*H
#define NHID_ 128
#define KD_   10000   // L_*DH_
#define KDP_  10240   // padded K for dense1 MFMA
#define NSPL_ 16      // dense1 split-K slices (640 K each)

typedef __attribute__((ext_vector_type(8))) short short8;
typedef __attribute__((ext_vector_type(4))) float f32x4;

// ---------- helpers ----------
__device__ __forceinline__ float sigf(float x){ return 1.f/(1.f+expf(-x)); }
__device__ __forceinline__ unsigned short f2bf(float f){
  unsigned int x = __float_as_uint(f);
  unsigned int r = x + 0x7fffu + ((x>>16)&1u);   // RNE
  return (unsigned short)(r>>16);
}
__device__ __forceinline__ float bf2f(unsigned short u){
  return __uint_as_float(((unsigned int)u)<<16);
}
__device__ __forceinline__ void load_lds16(const void* g, void* l){
  // 16B per lane, LDS dst = wave-uniform base + lane*16
  __builtin_amdgcn_global_load_lds((const __attribute__((address_space(1))) void*)g,
                                   (__attribute__((address_space(3))) void*)l, 16, 0, 0);
}

// =====================================================================
// K0: pack weights to bf16 padded layouts
//  wihp  [2][400][256] bf16 (K 243->256 zero pad)
//  bihp  [800] = bih+bhh (fwd | bwd)
//  wqkvp [3][224][224] bf16
//  bqkvp [3][224]
//  whhpk [2][448][128] bf16
//  dw1p  [128][10240] bf16
//  cwp   [192][512] bf16, tau-major k = tau*64 + c: rows 0-59 k2 (tau<2),
//        60-119 k3 (tau<3), 120-179 k8 (tau<8), 180-191 zero
//  cwb   [192] fp32 conv bias
// =====================================================================
__global__ __launch_bounds__(256) void k_pack(
    const float* __restrict__ wih_f, const float* __restrict__ bih_f, const float* __restrict__ bhh_f,
    const float* __restrict__ wih_b, const float* __restrict__ bih_b, const float* __restrict__ bhh_b,
    const float* __restrict__ whh_f, const float* __restrict__ whh_b,
    const float* __restrict__ wq, const float* __restrict__ bq,
    const float* __restrict__ wk, const float* __restrict__ bk,
    const float* __restrict__ wv, const float* __restrict__ bv,
    const float* __restrict__ dw1,
    const float* __restrict__ cw2, const float* __restrict__ cb2,
    const float* __restrict__ cw3, const float* __restrict__ cb3,
    const float* __restrict__ cw8, const float* __restrict__ cb8,
    unsigned short* __restrict__ wihp, float* __restrict__ bihp,
    unsigned short* __restrict__ wqkvp, float* __restrict__ bqkvp,
    unsigned short* __restrict__ whhpk, unsigned short* __restrict__ dw1p,
    unsigned short* __restrict__ cwp, float* __restrict__ cwb)
{
  int i = blockIdx.x*256 + threadIdx.x;
  if (i < 204800) {
    int d = i / 102400, rem = i % 102400, r = rem >> 8, k = rem & 255;
    const float* src = d ? wih_b : wih_f;
    wihp[i] = f2bf((k < 243) ? src[r*243 + k] : 0.f);
  } else if ((i -= 204800) < 800) {
    bihp[i] = (i < 400) ? (bih_f[i] + bhh_f[i]) : (bih_b[i-400] + bhh_b[i-400]);
  } else if ((i -= 800) < 150528) {
    int s = i / 50176, rem = i % 50176, n = rem / 224, k = rem % 224;
    const float* w = (s==0) ? wq : (s==1) ? wk : wv;
    wqkvp[i] = f2bf((n < 200 && k < 200) ? w[n*200 + k] : 0.f);
  } else if ((i -= 150528) < 672) {
    int s = i / 224, n = i % 224;
    const float* bb = (s==0) ? bq : (s==1) ? bk : bv;
    bqkvp[i] = (n < 200) ? bb[n] : 0.f;
  } else if ((i -= 672) < 114688) {
    int d = i / 57344, rem = i % 57344, n = rem >> 7, k = rem & 127;
    const float* src = d ? whh_b : whh_f;
    whhpk[i] = f2bf((n < 400 && k < 100) ? src[n*100 + k] : 0.f);
  } else if ((i -= 114688) < 1310720) {
    int n = i / KDP_, k = i % KDP_;
    dw1p[i] = f2bf((k < KD_) ? dw1[(size_t)n*KD_ + k] : 0.f);
  } else if ((i -= 1310720) < 98304) {
    int n = i >> 9, k = i & 511;
    int tau = k >> 6, c = k & 63;
    float v = 0.f;
    if (c < 63) {
      if (n < 60)       { if (tau < 2) v = cw2[(n*63 + c)*2 + tau]; }
      else if (n < 120) { if (tau < 3) v = cw3[((n-60)*63 + c)*3 + tau]; }
      else if (n < 180) { if (tau < 8) v = cw8[((n-120)*63 + c)*8 + tau]; }
    }
    cwp[i] = f2bf(v);
  } else if ((i -= 98304) < 192) {
    cwb[i] = (i < 60) ? cb2[i] : (i < 120) ? cb3[i-60] : (i < 180) ? cb8[i-120] : 0.f;
  }
}

// =====================================================================
// K1: embedding + fused 3-branch conv via MFMA + relu + maxpool
//     -> seq bf16 [B*L][256]
// Block = 2 batch elements. M=128 (2 x 64 t-rows), N=192, K=512 (tau-major).
// A-frags read DIRECTLY from x0T (im2col never materialized).
// dynamic LDS = 20736 (x0T [2][72][72]) + 12288 (Wst [4][192][8])
//             + 38400 (ys [2][50][192]) = 71424 B
// =====================================================================
__global__ __launch_bounds__(256) void k_embconv2(
    const int* __restrict__ x, const float* __restrict__ emb1, const float* __restrict__ emb2,
    const unsigned short* __restrict__ cwp, const float* __restrict__ cwb,
    unsigned short* __restrict__ seq)
{
  extern __shared__ char smem[];
  unsigned short (*x0T)[72][72]  = (unsigned short(*)[72][72])smem;             // [2][t][c]
  unsigned short (*Wst)[192][8]  = (unsigned short(*)[192][8])(smem + 20736);   // [cc][n][8]
  unsigned short (*ys)[50][192]  = (unsigned short(*)[50][192])(smem + 33024);  // [2][t][n]
  const int tid = threadIdx.x;
  const int lane = tid & 63, w = tid >> 6;
  const int r16 = lane & 15, c4 = lane >> 4;
  const int b0 = blockIdx.x * 2;

  // ---- phase 1: embedding -> x0T (transposed, bf16, zero-padded) ----
  for (int idx = tid; idx < 2*72*72; idx += 256) {
    int lb = idx / 5184, rem = idx % 5184, t = rem / 72, c = rem % 72;
    float v = 0.f;
    if (t < L_ && c < EMB_) {
      int e = x[(b0+lb)*L_ + t];
      v = (c < 21) ? emb1[e*21 + c] : emb2[e*42 + (c-21)];
    }
    x0T[lb][t][c] = f2bf(v);
  }
  __syncthreads();

  // ---- phase 2: x0 part of seq (cols 0..62) + pad cols 243..255 ----
  for (int idx = tid; idx < 2*L_*EMB_; idx += 256) {
    int lb = idx / (L_*EMB_), rem = idx % (L_*EMB_), l = rem / EMB_, c = rem % EMB_;
    seq[((size_t)(b0+lb)*L_ + l)*256 + c] = x0T[lb][l][c];
  }
  for (int idx = tid; idx < 2*L_*13; idx += 256) {
    int lb = idx / (L_*13), rem = idx % (L_*13), l = rem / 13, p = rem % 13;
    seq[((size_t)(b0+lb)*L_ + l)*256 + 243 + p] = 0;
  }

  // ---- phase 3: conv GEMM y[row][n] = sum_k A[row][k] * cwp[n][k] ----
  f32x4 acc[2][12];
  #pragma unroll
  for (int i = 0; i < 2; ++i)
    #pragma unroll
    for (int j = 0; j < 12; ++j) acc[i][j] = (f32x4){0.f,0.f,0.f,0.f};

  for (int ks = 0; ks < 16; ++ks) {
    const int k0 = ks*32;
    const int tau = ks >> 1, c0 = (ks & 1)*32;
    // stage Wst[cc][n] <- cwp[n][k0+cc*8] : 768 16B units, linear dest
    #pragma unroll
    for (int it = 0; it < 3; ++it) {
      const int u0 = it*256 + w*64;
      const int u = u0 + lane;
      const int cc = u / 192, n = u % 192;
      load_lds16(&cwp[(size_t)n*512 + k0 + cc*8], (char*)Wst + (size_t)u0*16);
    }
    __syncthreads();
    #pragma unroll
    for (int mf = 0; mf < 2; ++mf) {
      const int row = w*32 + mf*16 + r16;
      const int lb = row >> 6, t = row & 63;
      short8 a = *(const short8*)&x0T[lb][t + tau][c0 + c4*8];
      #pragma unroll
      for (int nf = 0; nf < 12; ++nf) {
        if (nf < 3 ? (ks < 4) : (nf < 7 ? (ks < 6) : true)) {
          short8 bfr = *(const short8*)&Wst[c4][nf*16 + r16][0];
          acc[mf][nf] = __builtin_amdgcn_mfma_f32_16x16x32_bf16(a, bfr, acc[mf][nf], 0, 0, 0);
        }
      }
    }
    __syncthreads();
  }

  // ---- phase 4: bias + relu -> ys (bf16) ----
  const int rg = lane >> 4;
  #pragma unroll
  for (int mf = 0; mf < 2; ++mf) {
    #pragma unroll
    for (int nf = 0; nf < 12; ++nf) {
      const int col = nf*16 + r16;
      const float bs = cwb[col];
      #pragma unroll
      for (int r = 0; r < 4; ++r) {
        const int row = w*32 + mf*16 + rg*4 + r;
        const int lb = row >> 6, t = row & 63;
        if (t < L_) ys[lb][t][col] = f2bf(fmaxf(acc[mf][nf][r] + bs, 0.f));
      }
    }
  }
  __syncthreads();

  // ---- phase 5: maxpool(5, stride1, pad1) + zero-pad -> seq cols 63..242 ----
  // relu outputs >= 0: bf16 bit pattern is monotone for non-negatives -> ushort max
  for (int idx = tid; idx < 2*L_*180; idx += 256) {
    int lb = idx / 9000, rem = idx % 9000, l = rem / 180, n = rem % 180;
    int br = n / 60;
    int Lc = (br == 0) ? 49 : (br == 1) ? 48 : 43;
    unsigned short vm = 0;
    if (l < Lc - 2) {
      int lo = (l-1 < 0) ? 0 : l-1;
      int hi = (l+3 > Lc-1) ? Lc-1 : l+3;
      for (int t = lo; t <= hi; ++t) {
        unsigned short u = ys[lb][t][n];
        vm = (u > vm) ? u : vm;
      }
    }
    seq[((size_t)(b0+lb)*L_ + l)*256 + EMB_ + n] = vm;
  }
}

// =====================================================================
// bf16 MFMA GEMM: C(M, N) = act(A(M,KA) @ W(N,KA)^T + bias)
// =====================================================================
template<int NF, int KSTEPS, int ACT, int OUTMODE>
__global__ __launch_bounds__(256) void k_gemm_mfma(
    const unsigned short* __restrict__ A,
    const unsigned short* __restrict__ W,
    const float* __restrict__ bias,
    void* __restrict__ C, int Nstride, int Nreal)
{
  constexpr int BN = NF*16;
  constexpr int KA = KSTEPS*32;
  constexpr int TU = 512 + BN*4;       // 16B staging units per K-tile
  __shared__ __attribute__((aligned(16))) unsigned short As[512*8];
  __shared__ __attribute__((aligned(16))) unsigned short Ws[BN*32];
  const int tid = threadIdx.x;
  const int lane = tid & 63, w = tid >> 6;
  const int m0 = blockIdx.x*128, n0 = blockIdx.y*BN;
  const int c = lane >> 4, r16 = lane & 15;
  f32x4 acc[2][NF];
  #pragma unroll
  for (int i = 0; i < 2; ++i)
    #pragma unroll
    for (int j = 0; j < NF; ++j) acc[i][j] = (f32x4){0.f,0.f,0.f,0.f};

  for (int ks = 0; ks < KSTEPS; ++ks) {
    const int k0 = ks*32;
    #pragma unroll
    for (int it = 0; it*256 < TU; ++it) {
      const int u0 = it*256 + w*64;           // wave-uniform
      if (u0 < TU) {
        if (u0 < 512) {
          const int u = u0 + lane;
          const int cc = u >> 7, row = u & 127;
          load_lds16(&A[(size_t)(m0+row)*KA + k0 + cc*8], (char*)As + (size_t)u0*16);
        } else {
          const int v2 = u0 - 512 + lane;
          const int n = v2 >> 2, cc = v2 & 3;
          load_lds16(&W[(size_t)(n0+n)*KA + k0 + cc*8], (char*)Ws + (size_t)(u0-512)*16);
        }
      }
    }
    __syncthreads();   // compiler drains vmcnt before barrier
    short8 a0 = *(const short8*)&As[(c*128 + w*32 + r16)*8];
    short8 a1 = *(const short8*)&As[(c*128 + w*32 + 16 + r16)*8];
    #pragma unroll
    for (int nf = 0; nf < NF; ++nf) {
      short8 bfr = *(const short8*)&Ws[((nf*16 + r16)*4 + c)*8];
      acc[0][nf] = __builtin_amdgcn_mfma_f32_16x16x32_bf16(a0, bfr, acc[0][nf], 0, 0, 0);
      acc[1][nf] = __builtin_amdgcn_mfma_f32_16x16x32_bf16(a1, bfr, acc[1][nf], 0, 0, 0);
    }
    __syncthreads();
  }
  // epilogue: C/D frag mapping col=lane&15, row=(lane>>4)*4+r
  const int rg = lane >> 4;
  #pragma unroll
  for (int mf = 0; mf < 2; ++mf) {
    #pragma unroll
    for (int nf = 0; nf < NF; ++nf) {
      const int colp = n0 + nf*16 + r16;
      const float bs = bias[colp];
      #pragma unroll
      for (int r = 0; r < 4; ++r) {
        const int row = m0 + w*32 + mf*16 + rg*4 + r;
        float val = acc[mf][nf][r] + bs;
        if (ACT == 1) val = sigf(val);
        else if (ACT == 2) val = expf(val);
        if (OUTMODE == 0) {
          if (colp < Nreal) ((float*)C)[(size_t)row*Nstride + colp] = val;
        } else {
          ((unsigned short*)C)[(size_t)row*Nstride + colp] = f2bf(val);
        }
      }
    }
  }
}

// =====================================================================
// Persistent bidirectional LSTM scan — MFMA recurrence.
// =====================================================================
__global__ __launch_bounds__(256) void k_scan(
    const unsigned short* __restrict__ gx,     // [B*L][800] bf16
    const unsigned short* __restrict__ whhpk,  // [2][448][128] bf16
    unsigned short* __restrict__ hout)         // [B*L][224] bf16
{
  __shared__ __attribute__((aligned(16))) unsigned short h_s[16][136];
  __shared__ float g_s[8][448];
  const int dir = blockIdx.y;
  const int b0 = blockIdx.x * 8;
  const int tid = threadIdx.x;
  const int lane = tid & 63, w = tid >> 6;
  const int r16 = lane & 15, c = lane >> 4;

  short8 bfr[7][4];
  {
    const unsigned short* wb = whhpk + (size_t)dir*448*128;
    #pragma unroll
    for (int nf = 0; nf < 7; ++nf)
      #pragma unroll
      for (int ks = 0; ks < 4; ++ks)
        bfr[nf][ks] = *(const short8*)&wb[(size_t)(w*112 + nf*16 + r16)*128 + ks*32 + c*8];
  }
  for (int idx = tid; idx < 16*136; idx += 256) ((unsigned short*)h_s)[idx] = 0;
  float cst[4] = {0.f,0.f,0.f,0.f};
  const int kh = tid % 100;
  const int r0 = tid / 100;
  const bool pbact = (tid < 200);
  __syncthreads();

  for (int t = 0; t < L_; ++t) {
    const int tp = dir ? (L_-1-t) : t;
    f32x4 acc[7];
    #pragma unroll
    for (int nf = 0; nf < 7; ++nf) acc[nf] = (f32x4){0.f,0.f,0.f,0.f};
    short8 afr[4];
    #pragma unroll
    for (int ks = 0; ks < 4; ++ks)
      afr[ks] = *(const short8*)&h_s[r16][ks*32 + c*8];
    #pragma unroll
    for (int ks = 0; ks < 4; ++ks)
      #pragma unroll
      for (int nf = 0; nf < 7; ++nf)
        acc[nf] = __builtin_amdgcn_mfma_f32_16x16x32_bf16(afr[ks], bfr[nf][ks], acc[nf], 0, 0, 0);
    unsigned short gxr[4][4];
    if (pbact) {
      #pragma unroll
      for (int i = 0; i < 4; ++i) {
        const int row = r0 + 2*i;
        const size_t gbase = ((size_t)(b0+row)*L_ + tp)*800 + (size_t)dir*400 + kh;
        #pragma unroll
        for (int g = 0; g < 4; ++g) gxr[i][g] = gx[gbase + 100*g];
      }
    }
    if (c < 2) {
      #pragma unroll
      for (int nf = 0; nf < 7; ++nf) {
        const int col = w*112 + nf*16 + r16;
        #pragma unroll
        for (int r = 0; r < 4; ++r)
          g_s[c*4 + r][col] = acc[nf][r];
      }
    }
    __syncthreads();
    if (pbact) {
      #pragma unroll
      for (int i = 0; i < 4; ++i) {
        const int row = r0 + 2*i;
        float gi = g_s[row][kh]       + bf2f(gxr[i][0]);
        float gf = g_s[row][kh + 100] + bf2f(gxr[i][1]);
        float gg = g_s[row][kh + 200] + bf2f(gxr[i][2]);
        float go = g_s[row][kh + 300] + bf2f(gxr[i][3]);
        float cn = sigf(gf)*cst[i] + sigf(gi)*tanhf(gg);
        cst[i] = cn;
        float hn = sigf(go)*tanhf(cn);
        unsigned short hb16 = f2bf(hn);
        h_s[row][kh] = hb16;
        hout[((size_t)(b0+row)*L_ + tp)*224 + dir*H_ + kh] = hb16;
      }
    }
    if (dir == 0 && tid < 192) {
      int r = tid / 24, p = tid - (tid/24)*24;
      hout[((size_t)(b0+r)*L_ + tp)*224 + 200 + p] = 0;
    }
    __syncthreads();
  }
}

// =====================================================================
// AFT attention: ek/ek*v staged bf16 in LDS (51.2 KB -> 3 blocks/CU).
// Output att bf16 [1024][10240] (pad-zeroed).
// =====================================================================
__global__ __launch_bounds__(256) void k_attn(
    const float* __restrict__ sq, const float* __restrict__ ek, const float* __restrict__ v,
    const float* __restrict__ pos_bias, unsigned short* __restrict__ att)
{
  extern __shared__ char smem[];
  unsigned short* eks = (unsigned short*)smem;          // [50][200] bf16
  unsigned short* evs = eks + L_*DH_;                   // [50][200] bf16
  float* wpT = (float*)(smem + 40000);                  // [50][56] fp32
  const int b = blockIdx.x, tid = threadIdx.x;
  const size_t base = (size_t)b*KD_;
  const size_t obase = (size_t)b*KDP_;
  for (int idx = tid; idx < L_*DH_; idx += 256) {
    float e = ek[base + idx];
    eks[idx] = f2bf(e);
    evs[idx] = f2bf(e * v[base + idx]);
  }
  for (int idx = tid; idx < 50*56; idx += 256) {
    int j = idx / 56, i = idx - (idx/56)*56;
    wpT[idx] = (i < L_) ? expf(pos_bias[i*L_ + j]) : 0.f;
  }
  __syncthreads();
  if (tid < 175) {
    const int ioct = tid / 25, doct = tid - (tid/25)*25;
    const int i0 = ioct*8, d0 = doct*8;
    float num[8][8], den[8][8];
    #pragma unroll
    for (int i = 0; i < 8; ++i)
      #pragma unroll
      for (int j = 0; j < 8; ++j) { num[i][j] = 0.f; den[i][j] = 0.f; }
    for (int j = 0; j < L_; ++j) {
      float wv8[8], ee8[8], ev8[8];
      *(float4*)&wv8[0] = *(const float4*)&wpT[j*56 + i0];
      *(float4*)&wv8[4] = *(const float4*)&wpT[j*56 + i0 + 4];
      short8 ee = *(const short8*)&eks[j*DH_ + d0];
      short8 ev = *(const short8*)&evs[j*DH_ + d0];
      #pragma unroll
      for (int u = 0; u < 8; ++u) {
        ee8[u] = bf2f((unsigned short)ee[u]);
        ev8[u] = bf2f((unsigned short)ev[u]);
      }
      #pragma unroll
      for (int ii = 0; ii < 8; ++ii)
        #pragma unroll
        for (int dd = 0; dd < 8; ++dd) {
          num[ii][dd] = fmaf(wv8[ii], ev8[dd], num[ii][dd]);
          den[ii][dd] = fmaf(wv8[ii], ee8[dd], den[ii][dd]);
        }
    }
    for (int ii = 0; ii < 8; ++ii) {
      int i = i0 + ii;
      if (i >= L_) break;
      #pragma unroll
      for (int d4 = 0; d4 < 2; ++d4) {
        int d = d0 + d4*4;
        float4 s4 = *(const float4*)&sq[base + (size_t)i*DH_ + d];
        att[obase + (size_t)i*DH_ + d + 0] = f2bf(s4.x * num[ii][d4*4+0] / den[ii][d4*4+0]);
        att[obase + (size_t)i*DH_ + d + 1] = f2bf(s4.y * num[ii][d4*4+1] / den[ii][d4*4+1]);
        att[obase + (size_t)i*DH_ + d + 2] = f2bf(s4.z * num[ii][d4*4+2] / den[ii][d4*4+2]);
        att[obase + (size_t)i*DH_ + d + 3] = f2bf(s4.w * num[ii][d4*4+3] / den[ii][d4*4+3]);
      }
    }
  }
  for (int idx = tid; idx < KDP_ - KD_; idx += 256) att[obase + KD_ + idx] = 0;
}

// =====================================================================
// dense1 via bf16 MFMA, split-K. grid (8, 16). part[16][1024][128] fp32.
// =====================================================================
__global__ __launch_bounds__(256) void k_dense1m(
    const unsigned short* __restrict__ att,   // [1024][10240] bf16
    const unsigned short* __restrict__ dw1p,  // [128][10240] bf16
    float* __restrict__ part)
{
  __shared__ __attribute__((aligned(16))) unsigned short As[512*8];
  __shared__ __attribute__((aligned(16))) unsigned short Ws[128*32];
  const int tid = threadIdx.x;
  const int lane = tid & 63, w = tid >> 6;
  const int m0 = blockIdx.x*128;
  const int koff = blockIdx.y*640;
  const int c = lane >> 4, r16 = lane & 15;
  f32x4 acc[2][8];
  #pragma unroll
  for (int i = 0; i < 2; ++i)
    #pragma unroll
    for (int j = 0; j < 8; ++j) acc[i][j] = (f32x4){0.f,0.f,0.f,0.f};

  for (int ks = 0; ks < 20; ++ks) {
    const int k0 = koff + ks*32;
    #pragma unroll
    for (int it = 0; it < 4; ++it) {
      const int u0 = it*256 + w*64;
      if (u0 < 512) {
        const int u = u0 + lane;
        const int cc = u >> 7, row = u & 127;
        load_lds16(&att[(size_t)(m0+row)*KDP_ + k0 + cc*8], (char*)As + (size_t)u0*16);
      } else {
        const int v2 = u0 - 512 + lane;
        const int n = v2 >> 2, cc = v2 & 3;
        load_lds16(&dw1p[(size_t)n*KDP_ + k0 + cc*8], (char*)Ws + (size_t)(u0-512)*16);
      }
    }
    __syncthreads();
    short8 a0 = *(const short8*)&As[(c*128 + w*32 + r16)*8];
    short8 a1 = *(const short8*)&As[(c*128 + w*32 + 16 + r16)*8];
    #pragma unroll
    for (int nf = 0; nf < 8; ++nf) {
      short8 bfr = *(const short8*)&Ws[((nf*16 + r16)*4 + c)*8];
      acc[0][nf] = __builtin_amdgcn_mfma_f32_16x16x32_bf16(a0, bfr, acc[0][nf], 0, 0, 0);
      acc[1][nf] = __builtin_amdgcn_mfma_f32_16x16x32_bf16(a1, bfr, acc[1][nf], 0, 0, 0);
    }
    __syncthreads();
  }
  const int rg = lane >> 4;
  #pragma unroll
  for (int mf = 0; mf < 2; ++mf)
    #pragma unroll
    for (int nf = 0; nf < 8; ++nf) {
      const int col = nf*16 + r16;
      #pragma unroll
      for (int r = 0; r < 4; ++r) {
        const int row = m0 + w*32 + mf*16 + rg*4 + r;
        part[((size_t)blockIdx.y*B_ + row)*NHID_ + col] = acc[mf][nf][r];
      }
    }
}

// =====================================================================
// dense2: reduce 16 split-K partials + bias + relu, then 128->5 + sigmoid
// =====================================================================
__global__ __launch_bounds__(128) void k_dense2(
    const float* __restrict__ part, const float* __restrict__ db1,
    const float* __restrict__ dw2, const float* __restrict__ db2,
    float* __restrict__ out)
{
  __shared__ float hid[NHID_];
  const int b = blockIdx.x, o = threadIdx.x;
  float s = db1[o];
  #pragma unroll
  for (int sl = 0; sl < NSPL_; ++sl) s += part[((size_t)sl*B_ + b)*NHID_ + o];
  hid[o] = fmaxf(s, 0.f);
  __syncthreads();
  if (o < 5) {
    float acc = db2[o];
    for (int j = 0; j < NHID_; ++j) acc = fmaf(hid[j], dw2[o*NHID_ + j], acc);
    out[b*5 + o] = sigf(acc);
  }
}

// =====================================================================
extern "C" void kernel_launch(void* const* d_in, const int* in_sizes, int n_in,
                              void* d_out, int out_size, void* d_ws, size_t ws_size,
                              hipStream_t stream)
{
  const int*   x     = (const int*)  d_in[0];
  const float* emb1  = (const float*)d_in[1];
  const float* emb2  = (const float*)d_in[2];
  const float* cw2   = (const float*)d_in[3];
  const float* cb2   = (const float*)d_in[4];
  const float* cw3   = (const float*)d_in[5];
  const float* cb3   = (const float*)d_in[6];
  const float* cw8   = (const float*)d_in[7];
  const float* cb8   = (const float*)d_in[8];
  const float* wih_f = (const float*)d_in[9];
  const float* whh_f = (const float*)d_in[10];
  const float* bih_f = (const float*)d_in[11];
  const float* bhh_f = (const float*)d_in[12];
  const float* wih_b = (const float*)d_in[13];
  const float* whh_b = (const float*)d_in[14];
  const float* bih_b = (const float*)d_in[15];
  const float* bhh_b = (const float*)d_in[16];
  const float* wq    = (const float*)d_in[17];
  const float* bq    = (const float*)d_in[18];
  const float* wk    = (const float*)d_in[19];
  const float* bk    = (const float*)d_in[20];
  const float* wv    = (const float*)d_in[21];
  const float* bv    = (const float*)d_in[22];
  const float* pos_bias = (const float*)d_in[23];
  const float* dw1   = (const float*)d_in[24];
  const float* db1   = (const float*)d_in[25];
  const float* dw2   = (const float*)d_in[26];
  const float* db2   = (const float*)d_in[27];
  (void)in_sizes; (void)n_in; (void)out_size;

  // ---- workspace layout (bytes, 256-aligned) ----
  char* base = (char*)d_ws;
  size_t off = 0;
  auto alloc = [&](size_t bytes) -> char* {
    char* p = base + off;
    off = (off + bytes + 255) & ~(size_t)255;
    return p;
  };
  unsigned short* seqb  = (unsigned short*)alloc(51200UL*256*2);   // 26.2 MB
  unsigned short* gxb   = (unsigned short*)alloc(51200UL*800*2);   // 81.9 MB
  unsigned short* hb    = (unsigned short*)alloc(51200UL*224*2);   // 22.9 MB
  float*          sqb   = (float*)alloc(51200UL*200*4);            // 41.0 MB
  float*          ekb   = (float*)alloc(51200UL*200*4);            // 41.0 MB
  float*          vb    = (float*)alloc(51200UL*200*4);            // 41.0 MB
  unsigned short* wihp  = (unsigned short*)alloc(204800UL*2);
  float*          bihp  = (float*)alloc(800UL*4);
  unsigned short* wqkvp = (unsigned short*)alloc(150528UL*2);
  float*          bqkvp = (float*)alloc(672UL*4);
  unsigned short* whhpk = (unsigned short*)alloc(114688UL*2);
  unsigned short* dw1p  = (unsigned short*)alloc(1310720UL*2);     // 2.6 MB
  unsigned short* cwp   = (unsigned short*)alloc(98304UL*2);
  float*          cwb   = (float*)alloc(192UL*4);
  if (off > ws_size) return;                 // ~258 MB total
  unsigned short* attb = (unsigned short*)gxb; // overlay: gx dead after scan
  float* part = (float*)seqb;                  // overlay: seq dead after gx GEMM

  hipFuncSetAttribute(reinterpret_cast<const void*>(k_attn),
                      hipFuncAttributeMaxDynamicSharedMemorySize, 51200);
  hipFuncSetAttribute(reinterpret_cast<const void*>(k_embconv2),
                      hipFuncAttributeMaxDynamicSharedMemorySize, 71424);

  k_pack<<<dim3(7347), 256, 0, stream>>>(wih_f, bih_f, bhh_f, wih_b, bih_b, bhh_b,
                                         whh_f, whh_b, wq, bq, wk, bk, wv, bv, dw1,
                                         cw2, cb2, cw3, cb3, cw8, cb8,
                                         wihp, bihp, wqkvp, bqkvp, whhpk, dw1p, cwp, cwb);
  k_embconv2<<<dim3(512), 256, 71424, stream>>>(x, emb1, emb2, cwp, cwb, seqb);
  // gx = seq @ [wih_f|wih_b]^T + biases  -> bf16 (M=51200, N=800, K=256)
  k_gemm_mfma<5, 8, 0, 1><<<dim3(400, 10), 256, 0, stream>>>(seqb, wihp, bihp, gxb, 800, 800);
  k_scan<<<dim3(128, 2), 256, 0, stream>>>(gxb, whhpk, hb);
  // q/k/v GEMMs (M=51200, N=200 pad 224, K=224), epilogue sigmoid/exp/none
  k_gemm_mfma<7, 7, 1, 0><<<dim3(400, 2), 256, 0, stream>>>(hb, wqkvp,          bqkvp,       sqb, 200, 200);
  k_gemm_mfma<7, 7, 2, 0><<<dim3(400, 2), 256, 0, stream>>>(hb, wqkvp + 50176,  bqkvp + 224, ekb, 200, 200);
  k_gemm_mfma<7, 7, 0, 0><<<dim3(400, 2), 256, 0, stream>>>(hb, wqkvp + 100352, bqkvp + 448, vb,  200, 200);
  k_attn<<<dim3(1024), 256, 51200, stream>>>(sqb, ekb, vb, pos_bias, attb);
  k_dense1m<<<dim3(8, NSPL_), 256, 0, stream>>>(attb, dw1p, part);
  k_dense2<<<dim3(1024), 128, 0, stream>>>(part, db1, dw2, db2, (float*)d_out);
}

// Round 12
// 469.561 us; speedup vs baseline: 7.3422x; 1.0365x over previous
//
#include <hip/hip_runtime.h>
#include <cstdint>
#include <cstddef>

// ---- model dims ----
#define B_    1024
#define L_    50
#define EMB_  63
#define CD_   60
#define H_    100
#define G4_   400     // 4*H
#define DH_   200     // 2*H
#define NHID_ 128
#define KD_   10000   // L_*DH_
#define KDP_  10240   // padded K for dense1 MFMA
#define NSPL_ 16      // dense1 split-K slices (640 K each)

typedef __attribute__((ext_vector_type(8))) short short8;
typedef __attribute__((ext_vector_type(4))) float f32x4;

// ---------- helpers ----------
__device__ __forceinline__ float sigf(float x){ return 1.f/(1.f+expf(-x)); }
__device__ __forceinline__ unsigned short f2bf(float f){
  unsigned int x = __float_as_uint(f);
  unsigned int r = x + 0x7fffu + ((x>>16)&1u);   // RNE
  return (unsigned short)(r>>16);
}
__device__ __forceinline__ float bf2f(unsigned short u){
  return __uint_as_float(((unsigned int)u)<<16);
}
__device__ __forceinline__ void load_lds16(const void* g, void* l){
  // 16B per lane, LDS dst = wave-uniform base + lane*16
  __builtin_amdgcn_global_load_lds((const __attribute__((address_space(1))) void*)g,
                                   (__attribute__((address_space(3))) void*)l, 16, 0, 0);
}

// =====================================================================
// K0: pack weights to bf16 padded layouts
// =====================================================================
__global__ __launch_bounds__(256) void k_pack(
    const float* __restrict__ wih_f, const float* __restrict__ bih_f, const float* __restrict__ bhh_f,
    const float* __restrict__ wih_b, const float* __restrict__ bih_b, const float* __restrict__ bhh_b,
    const float* __restrict__ whh_f, const float* __restrict__ whh_b,
    const float* __restrict__ wq, const float* __restrict__ bq,
    const float* __restrict__ wk, const float* __restrict__ bk,
    const float* __restrict__ wv, const float* __restrict__ bv,
    const float* __restrict__ dw1,
    const float* __restrict__ cw2, const float* __restrict__ cb2,
    const float* __restrict__ cw3, const float* __restrict__ cb3,
    const float* __restrict__ cw8, const float* __restrict__ cb8,
    unsigned short* __restrict__ wihp, float* __restrict__ bihp,
    unsigned short* __restrict__ wqkvp, float* __restrict__ bqkvp,
    unsigned short* __restrict__ whhpk, unsigned short* __restrict__ dw1p,
    unsigned short* __restrict__ cwp, float* __restrict__ cwb)
{
  int i = blockIdx.x*256 + threadIdx.x;
  if (i < 204800) {
    int d = i / 102400, rem = i % 102400, r = rem >> 8, k = rem & 255;
    const float* src = d ? wih_b : wih_f;
    wihp[i] = f2bf((k < 243) ? src[r*243 + k] : 0.f);
  } else if ((i -= 204800) < 800) {
    bihp[i] = (i < 400) ? (bih_f[i] + bhh_f[i]) : (bih_b[i-400] + bhh_b[i-400]);
  } else if ((i -= 800) < 150528) {
    int s = i / 50176, rem = i % 50176, n = rem / 224, k = rem % 224;
    const float* w = (s==0) ? wq : (s==1) ? wk : wv;
    wqkvp[i] = f2bf((n < 200 && k < 200) ? w[n*200 + k] : 0.f);
  } else if ((i -= 150528) < 672) {
    int s = i / 224, n = i % 224;
    const float* bb = (s==0) ? bq : (s==1) ? bk : bv;
    bqkvp[i] = (n < 200) ? bb[n] : 0.f;
  } else if ((i -= 672) < 114688) {
    int d = i / 57344, rem = i % 57344, n = rem >> 7, k = rem & 127;
    const float* src = d ? whh_b : whh_f;
    whhpk[i] = f2bf((n < 400 && k < 100) ? src[n*100 + k] : 0.f);
  } else if ((i -= 114688) < 1310720) {
    int n = i / KDP_, k = i % KDP_;
    dw1p[i] = f2bf((k < KD_) ? dw1[(size_t)n*KD_ + k] : 0.f);
  } else if ((i -= 1310720) < 98304) {
    int n = i >> 9, k = i & 511;
    int tau = k >> 6, c = k & 63;
    float v = 0.f;
    if (c < 63) {
      if (n < 60)       { if (tau < 2) v = cw2[(n*63 + c)*2 + tau]; }
      else if (n < 120) { if (tau < 3) v = cw3[((n-60)*63 + c)*3 + tau]; }
      else if (n < 180) { if (tau < 8) v = cw8[((n-120)*63 + c)*8 + tau]; }
    }
    cwp[i] = f2bf(v);
  } else if ((i -= 98304) < 192) {
    cwb[i] = (i < 60) ? cb2[i] : (i < 120) ? cb3[i-60] : (i < 180) ? cb8[i-120] : 0.f;
  }
}

// =====================================================================
// K1: embedding + fused 3-branch conv via MFMA + relu + maxpool
//     -> seq bf16 [B*L][256]
// dynamic LDS = 20736 + 12288 + 38400 = 71424 B
// =====================================================================
__global__ __launch_bounds__(256) void k_embconv2(
    const int* __restrict__ x, const float* __restrict__ emb1, const float* __restrict__ emb2,
    const unsigned short* __restrict__ cwp, const float* __restrict__ cwb,
    unsigned short* __restrict__ seq)
{
  extern __shared__ char smem[];
  unsigned short (*x0T)[72][72]  = (unsigned short(*)[72][72])smem;             // [2][t][c]
  unsigned short (*Wst)[192][8]  = (unsigned short(*)[192][8])(smem + 20736);   // [cc][n][8]
  unsigned short (*ys)[50][192]  = (unsigned short(*)[50][192])(smem + 33024);  // [2][t][n]
  const int tid = threadIdx.x;
  const int lane = tid & 63, w = tid >> 6;
  const int r16 = lane & 15, c4 = lane >> 4;
  const int b0 = blockIdx.x * 2;

  for (int idx = tid; idx < 2*72*72; idx += 256) {
    int lb = idx / 5184, rem = idx % 5184, t = rem / 72, c = rem % 72;
    float v = 0.f;
    if (t < L_ && c < EMB_) {
      int e = x[(b0+lb)*L_ + t];
      v = (c < 21) ? emb1[e*21 + c] : emb2[e*42 + (c-21)];
    }
    x0T[lb][t][c] = f2bf(v);
  }
  __syncthreads();

  for (int idx = tid; idx < 2*L_*EMB_; idx += 256) {
    int lb = idx / (L_*EMB_), rem = idx % (L_*EMB_), l = rem / EMB_, c = rem % EMB_;
    seq[((size_t)(b0+lb)*L_ + l)*256 + c] = x0T[lb][l][c];
  }
  for (int idx = tid; idx < 2*L_*13; idx += 256) {
    int lb = idx / (L_*13), rem = idx % (L_*13), l = rem / 13, p = rem % 13;
    seq[((size_t)(b0+lb)*L_ + l)*256 + 243 + p] = 0;
  }

  f32x4 acc[2][12];
  #pragma unroll
  for (int i = 0; i < 2; ++i)
    #pragma unroll
    for (int j = 0; j < 12; ++j) acc[i][j] = (f32x4){0.f,0.f,0.f,0.f};

  for (int ks = 0; ks < 16; ++ks) {
    const int k0 = ks*32;
    const int tau = ks >> 1, c0 = (ks & 1)*32;
    #pragma unroll
    for (int it = 0; it < 3; ++it) {
      const int u0 = it*256 + w*64;
      const int u = u0 + lane;
      const int cc = u / 192, n = u % 192;
      load_lds16(&cwp[(size_t)n*512 + k0 + cc*8], (char*)Wst + (size_t)u0*16);
    }
    __syncthreads();
    #pragma unroll
    for (int mf = 0; mf < 2; ++mf) {
      const int row = w*32 + mf*16 + r16;
      const int lb = row >> 6, t = row & 63;
      short8 a = *(const short8*)&x0T[lb][t + tau][c0 + c4*8];
      #pragma unroll
      for (int nf = 0; nf < 12; ++nf) {
        if (nf < 3 ? (ks < 4) : (nf < 7 ? (ks < 6) : true)) {
          short8 bfr = *(const short8*)&Wst[c4][nf*16 + r16][0];
          acc[mf][nf] = __builtin_amdgcn_mfma_f32_16x16x32_bf16(a, bfr, acc[mf][nf], 0, 0, 0);
        }
      }
    }
    __syncthreads();
  }

  const int rg = lane >> 4;
  #pragma unroll
  for (int mf = 0; mf < 2; ++mf) {
    #pragma unroll
    for (int nf = 0; nf < 12; ++nf) {
      const int col = nf*16 + r16;
      const float bs = cwb[col];
      #pragma unroll
      for (int r = 0; r < 4; ++r) {
        const int row = w*32 + mf*16 + rg*4 + r;
        const int lb = row >> 6, t = row & 63;
        if (t < L_) ys[lb][t][col] = f2bf(fmaxf(acc[mf][nf][r] + bs, 0.f));
      }
    }
  }
  __syncthreads();

  for (int idx = tid; idx < 2*L_*180; idx += 256) {
    int lb = idx / 9000, rem = idx % 9000, l = rem / 180, n = rem % 180;
    int br = n / 60;
    int Lc = (br == 0) ? 49 : (br == 1) ? 48 : 43;
    unsigned short vm = 0;
    if (l < Lc - 2) {
      int lo = (l-1 < 0) ? 0 : l-1;
      int hi = (l+3 > Lc-1) ? Lc-1 : l+3;
      for (int t = lo; t <= hi; ++t) {
        unsigned short u = ys[lb][t][n];
        vm = (u > vm) ? u : vm;
      }
    }
    seq[((size_t)(b0+lb)*L_ + l)*256 + EMB_ + n] = vm;
  }
}

// =====================================================================
// bf16 MFMA GEMM: C(M, N) = act(A(M,KA) @ W(N,KA)^T + bias)
// =====================================================================
template<int NF, int KSTEPS, int ACT, int OUTMODE>
__global__ __launch_bounds__(256) void k_gemm_mfma(
    const unsigned short* __restrict__ A,
    const unsigned short* __restrict__ W,
    const float* __restrict__ bias,
    void* __restrict__ C, int Nstride, int Nreal)
{
  constexpr int BN = NF*16;
  constexpr int KA = KSTEPS*32;
  constexpr int TU = 512 + BN*4;       // 16B staging units per K-tile
  __shared__ __attribute__((aligned(16))) unsigned short As[512*8];
  __shared__ __attribute__((aligned(16))) unsigned short Ws[BN*32];
  const int tid = threadIdx.x;
  const int lane = tid & 63, w = tid >> 6;
  const int m0 = blockIdx.x*128, n0 = blockIdx.y*BN;
  const int c = lane >> 4, r16 = lane & 15;
  f32x4 acc[2][NF];
  #pragma unroll
  for (int i = 0; i < 2; ++i)
    #pragma unroll
    for (int j = 0; j < NF; ++j) acc[i][j] = (f32x4){0.f,0.f,0.f,0.f};

  for (int ks = 0; ks < KSTEPS; ++ks) {
    const int k0 = ks*32;
    #pragma unroll
    for (int it = 0; it*256 < TU; ++it) {
      const int u0 = it*256 + w*64;           // wave-uniform
      if (u0 < TU) {
        if (u0 < 512) {
          const int u = u0 + lane;
          const int cc = u >> 7, row = u & 127;
          load_lds16(&A[(size_t)(m0+row)*KA + k0 + cc*8], (char*)As + (size_t)u0*16);
        } else {
          const int v2 = u0 - 512 + lane;
          const int n = v2 >> 2, cc = v2 & 3;
          load_lds16(&W[(size_t)(n0+n)*KA + k0 + cc*8], (char*)Ws + (size_t)(u0-512)*16);
        }
      }
    }
    __syncthreads();   // compiler drains vmcnt before barrier
    short8 a0 = *(const short8*)&As[(c*128 + w*32 + r16)*8];
    short8 a1 = *(const short8*)&As[(c*128 + w*32 + 16 + r16)*8];
    #pragma unroll
    for (int nf = 0; nf < NF; ++nf) {
      short8 bfr = *(const short8*)&Ws[((nf*16 + r16)*4 + c)*8];
      acc[0][nf] = __builtin_amdgcn_mfma_f32_16x16x32_bf16(a0, bfr, acc[0][nf], 0, 0, 0);
      acc[1][nf] = __builtin_amdgcn_mfma_f32_16x16x32_bf16(a1, bfr, acc[1][nf], 0, 0, 0);
    }
    __syncthreads();
  }
  const int rg = lane >> 4;
  #pragma unroll
  for (int mf = 0; mf < 2; ++mf) {
    #pragma unroll
    for (int nf = 0; nf < NF; ++nf) {
      const int colp = n0 + nf*16 + r16;
      const float bs = bias[colp];
      #pragma unroll
      for (int r = 0; r < 4; ++r) {
        const int row = m0 + w*32 + mf*16 + rg*4 + r;
        float val = acc[mf][nf][r] + bs;
        if (ACT == 1) val = sigf(val);
        else if (ACT == 2) val = expf(val);
        if (OUTMODE == 0) {
          if (colp < Nreal) ((float*)C)[(size_t)row*Nstride + colp] = val;
        } else {
          ((unsigned short*)C)[(size_t)row*Nstride + colp] = f2bf(val);
        }
      }
    }
  }
}

// =====================================================================
// Persistent bidirectional LSTM scan — MFMA recurrence.
// NBR=4: grid (256, 2) = 512 blocks = 2 blocks/CU (was 1 -> latency-bound).
// 4 batch rows/block; M=16 MFMA tile rows 0-3 used; 2 gate rows per thread.
// =====================================================================
__global__ __launch_bounds__(256) void k_scan(
    const unsigned short* __restrict__ gx,     // [B*L][800] bf16
    const unsigned short* __restrict__ whhpk,  // [2][448][128] bf16
    unsigned short* __restrict__ hout)         // [B*L][224] bf16
{
  __shared__ __attribute__((aligned(16))) unsigned short h_s[16][136];
  __shared__ float g_s[4][448];
  const int dir = blockIdx.y;
  const int b0 = blockIdx.x * 4;
  const int tid = threadIdx.x;
  const int lane = tid & 63, w = tid >> 6;
  const int r16 = lane & 15, c = lane >> 4;

  short8 bfr[7][4];
  {
    const unsigned short* wb = whhpk + (size_t)dir*448*128;
    #pragma unroll
    for (int nf = 0; nf < 7; ++nf)
      #pragma unroll
      for (int ks = 0; ks < 4; ++ks)
        bfr[nf][ks] = *(const short8*)&wb[(size_t)(w*112 + nf*16 + r16)*128 + ks*32 + c*8];
  }
  for (int idx = tid; idx < 16*136; idx += 256) ((unsigned short*)h_s)[idx] = 0;
  float cst[2] = {0.f, 0.f};
  const int kh = tid % 100;
  const int r0 = tid / 100;          // 0 or 1 for active threads
  const bool pbact = (tid < 200);
  __syncthreads();

  for (int t = 0; t < L_; ++t) {
    const int tp = dir ? (L_-1-t) : t;
    // ---- phase A: g_mm = h @ whh^T via MFMA ----
    f32x4 acc[7];
    #pragma unroll
    for (int nf = 0; nf < 7; ++nf) acc[nf] = (f32x4){0.f,0.f,0.f,0.f};
    short8 afr[4];
    #pragma unroll
    for (int ks = 0; ks < 4; ++ks)
      afr[ks] = *(const short8*)&h_s[r16][ks*32 + c*8];
    #pragma unroll
    for (int ks = 0; ks < 4; ++ks)
      #pragma unroll
      for (int nf = 0; nf < 7; ++nf)
        acc[nf] = __builtin_amdgcn_mfma_f32_16x16x32_bf16(afr[ks], bfr[nf][ks], acc[nf], 0, 0, 0);
    // prefetch gx gates for phase B (rows r0, r0+2)
    unsigned short gxr[2][4];
    if (pbact) {
      #pragma unroll
      for (int i = 0; i < 2; ++i) {
        const int row = r0 + 2*i;
        const size_t gbase = ((size_t)(b0+row)*L_ + tp)*800 + (size_t)dir*400 + kh;
        #pragma unroll
        for (int g = 0; g < 4; ++g) gxr[i][g] = gx[gbase + 100*g];
      }
    }
    // write C frags (rows 0-3 <=> c==0): col=lane&15, row=(lane>>4)*4+r
    if (c == 0) {
      #pragma unroll
      for (int nf = 0; nf < 7; ++nf) {
        const int col = w*112 + nf*16 + r16;
        #pragma unroll
        for (int r = 0; r < 4; ++r)
          g_s[r][col] = acc[nf][r];
      }
    }
    __syncthreads();
    // ---- phase B: gates, c/h update (2 rows per active thread) ----
    if (pbact) {
      #pragma unroll
      for (int i = 0; i < 2; ++i) {
        const int row = r0 + 2*i;
        float gi = g_s[row][kh]       + bf2f(gxr[i][0]);
        float gf = g_s[row][kh + 100] + bf2f(gxr[i][1]);
        float gg = g_s[row][kh + 200] + bf2f(gxr[i][2]);
        float go = g_s[row][kh + 300] + bf2f(gxr[i][3]);
        float cn = sigf(gf)*cst[i] + sigf(gi)*tanhf(gg);
        cst[i] = cn;
        float hn = sigf(go)*tanhf(cn);
        unsigned short hb16 = f2bf(hn);
        h_s[row][kh] = hb16;
        hout[((size_t)(b0+row)*L_ + tp)*224 + dir*H_ + kh] = hb16;
      }
    }
    if (dir == 0 && tid < 96) {
      int r = tid / 24, p = tid - (tid/24)*24;
      hout[((size_t)(b0+r)*L_ + tp)*224 + 200 + p] = 0;
    }
    __syncthreads();
  }
}

// =====================================================================
// AFT attention: ek/ek*v staged bf16 in LDS (51.2 KB -> 3 blocks/CU).
// Output att bf16 [1024][10240] (pad-zeroed).
// =====================================================================
__global__ __launch_bounds__(256) void k_attn(
    const float* __restrict__ sq, const float* __restrict__ ek, const float* __restrict__ v,
    const float* __restrict__ pos_bias, unsigned short* __restrict__ att)
{
  extern __shared__ char smem[];
  unsigned short* eks = (unsigned short*)smem;          // [50][200] bf16
  unsigned short* evs = eks + L_*DH_;                   // [50][200] bf16
  float* wpT = (float*)(smem + 40000);                  // [50][56] fp32
  const int b = blockIdx.x, tid = threadIdx.x;
  const size_t base = (size_t)b*KD_;
  const size_t obase = (size_t)b*KDP_;
  for (int idx = tid; idx < L_*DH_; idx += 256) {
    float e = ek[base + idx];
    eks[idx] = f2bf(e);
    evs[idx] = f2bf(e * v[base + idx]);
  }
  for (int idx = tid; idx < 50*56; idx += 256) {
    int j = idx / 56, i = idx - (idx/56)*56;
    wpT[idx] = (i < L_) ? expf(pos_bias[i*L_ + j]) : 0.f;
  }
  __syncthreads();
  if (tid < 175) {
    const int ioct = tid / 25, doct = tid - (tid/25)*25;
    const int i0 = ioct*8, d0 = doct*8;
    float num[8][8], den[8][8];
    #pragma unroll
    for (int i = 0; i < 8; ++i)
      #pragma unroll
      for (int j = 0; j < 8; ++j) { num[i][j] = 0.f; den[i][j] = 0.f; }
    for (int j = 0; j < L_; ++j) {
      float wv8[8], ee8[8], ev8[8];
      *(float4*)&wv8[0] = *(const float4*)&wpT[j*56 + i0];
      *(float4*)&wv8[4] = *(const float4*)&wpT[j*56 + i0 + 4];
      short8 ee = *(const short8*)&eks[j*DH_ + d0];
      short8 ev = *(const short8*)&evs[j*DH_ + d0];
      #pragma unroll
      for (int u = 0; u < 8; ++u) {
        ee8[u] = bf2f((unsigned short)ee[u]);
        ev8[u] = bf2f((unsigned short)ev[u]);
      }
      #pragma unroll
      for (int ii = 0; ii < 8; ++ii)
        #pragma unroll
        for (int dd = 0; dd < 8; ++dd) {
          num[ii][dd] = fmaf(wv8[ii], ev8[dd], num[ii][dd]);
          den[ii][dd] = fmaf(wv8[ii], ee8[dd], den[ii][dd]);
        }
    }
    for (int ii = 0; ii < 8; ++ii) {
      int i = i0 + ii;
      if (i >= L_) break;
      #pragma unroll
      for (int d4 = 0; d4 < 2; ++d4) {
        int d = d0 + d4*4;
        float4 s4 = *(const float4*)&sq[base + (size_t)i*DH_ + d];
        att[obase + (size_t)i*DH_ + d + 0] = f2bf(s4.x * num[ii][d4*4+0] / den[ii][d4*4+0]);
        att[obase + (size_t)i*DH_ + d + 1] = f2bf(s4.y * num[ii][d4*4+1] / den[ii][d4*4+1]);
        att[obase + (size_t)i*DH_ + d + 2] = f2bf(s4.z * num[ii][d4*4+2] / den[ii][d4*4+2]);
        att[obase + (size_t)i*DH_ + d + 3] = f2bf(s4.w * num[ii][d4*4+3] / den[ii][d4*4+3]);
      }
    }
  }
  for (int idx = tid; idx < KDP_ - KD_; idx += 256) att[obase + KD_ + idx] = 0;
}

// =====================================================================
// dense1 via bf16 MFMA, split-K. grid (8, 16). part[16][1024][128] fp32.
// =====================================================================
__global__ __launch_bounds__(256) void k_dense1m(
    const unsigned short* __restrict__ att,   // [1024][10240] bf16
    const unsigned short* __restrict__ dw1p,  // [128][10240] bf16
    float* __restrict__ part)
{
  __shared__ __attribute__((aligned(16))) unsigned short As[512*8];
  __shared__ __attribute__((aligned(16))) unsigned short Ws[128*32];
  const int tid = threadIdx.x;
  const int lane = tid & 63, w = tid >> 6;
  const int m0 = blockIdx.x*128;
  const int koff = blockIdx.y*640;
  const int c = lane >> 4, r16 = lane & 15;
  f32x4 acc[2][8];
  #pragma unroll
  for (int i = 0; i < 2; ++i)
    #pragma unroll
    for (int j = 0; j < 8; ++j) acc[i][j] = (f32x4){0.f,0.f,0.f,0.f};

  for (int ks = 0; ks < 20; ++ks) {
    const int k0 = koff + ks*32;
    #pragma unroll
    for (int it = 0; it < 4; ++it) {
      const int u0 = it*256 + w*64;
      if (u0 < 512) {
        const int u = u0 + lane;
        const int cc = u >> 7, row = u & 127;
        load_lds16(&att[(size_t)(m0+row)*KDP_ + k0 + cc*8], (char*)As + (size_t)u0*16);
      } else {
        const int v2 = u0 - 512 + lane;
        const int n = v2 >> 2, cc = v2 & 3;
        load_lds16(&dw1p[(size_t)n*KDP_ + k0 + cc*8], (char*)Ws + (size_t)(u0-512)*16);
      }
    }
    __syncthreads();
    short8 a0 = *(const short8*)&As[(c*128 + w*32 + r16)*8];
    short8 a1 = *(const short8*)&As[(c*128 + w*32 + 16 + r16)*8];
    #pragma unroll
    for (int nf = 0; nf < 8; ++nf) {
      short8 bfr = *(const short8*)&Ws[((nf*16 + r16)*4 + c)*8];
      acc[0][nf] = __builtin_amdgcn_mfma_f32_16x16x32_bf16(a0, bfr, acc[0][nf], 0, 0, 0);
      acc[1][nf] = __builtin_amdgcn_mfma_f32_16x16x32_bf16(a1, bfr, acc[1][nf], 0, 0, 0);
    }
    __syncthreads();
  }
  const int rg = lane >> 4;
  #pragma unroll
  for (int mf = 0; mf < 2; ++mf)
    #pragma unroll
    for (int nf = 0; nf < 8; ++nf) {
      const int col = nf*16 + r16;
      #pragma unroll
      for (int r = 0; r < 4; ++r) {
        const int row = m0 + w*32 + mf*16 + rg*4 + r;
        part[((size_t)blockIdx.y*B_ + row)*NHID_ + col] = acc[mf][nf][r];
      }
    }
}

// =====================================================================
// dense2: reduce 16 split-K partials + bias + relu, then 128->5 + sigmoid
// =====================================================================
__global__ __launch_bounds__(128) void k_dense2(
    const float* __restrict__ part, const float* __restrict__ db1,
    const float* __restrict__ dw2, const float* __restrict__ db2,
    float* __restrict__ out)
{
  __shared__ float hid[NHID_];
  const int b = blockIdx.x, o = threadIdx.x;
  float s = db1[o];
  #pragma unroll
  for (int sl = 0; sl < NSPL_; ++sl) s += part[((size_t)sl*B_ + b)*NHID_ + o];
  hid[o] = fmaxf(s, 0.f);
  __syncthreads();
  if (o < 5) {
    float acc = db2[o];
    for (int j = 0; j < NHID_; ++j) acc = fmaf(hid[j], dw2[o*NHID_ + j], acc);
    out[b*5 + o] = sigf(acc);
  }
}

// =====================================================================
extern "C" void kernel_launch(void* const* d_in, const int* in_sizes, int n_in,
                              void* d_out, int out_size, void* d_ws, size_t ws_size,
                              hipStream_t stream)
{
  const int*   x     = (const int*)  d_in[0];
  const float* emb1  = (const float*)d_in[1];
  const float* emb2  = (const float*)d_in[2];
  const float* cw2   = (const float*)d_in[3];
  const float* cb2   = (const float*)d_in[4];
  const float* cw3   = (const float*)d_in[5];
  const float* cb3   = (const float*)d_in[6];
  const float* cw8   = (const float*)d_in[7];
  const float* cb8   = (const float*)d_in[8];
  const float* wih_f = (const float*)d_in[9];
  const float* whh_f = (const float*)d_in[10];
  const float* bih_f = (const float*)d_in[11];
  const float* bhh_f = (const float*)d_in[12];
  const float* wih_b = (const float*)d_in[13];
  const float* whh_b = (const float*)d_in[14];
  const float* bih_b = (const float*)d_in[15];
  const float* bhh_b = (const float*)d_in[16];
  const float* wq    = (const float*)d_in[17];
  const float* bq    = (const float*)d_in[18];
  const float* wk    = (const float*)d_in[19];
  const float* bk    = (const float*)d_in[20];
  const float* wv    = (const float*)d_in[21];
  const float* bv    = (const float*)d_in[22];
  const float* pos_bias = (const float*)d_in[23];
  const float* dw1   = (const float*)d_in[24];
  const float* db1   = (const float*)d_in[25];
  const float* dw2   = (const float*)d_in[26];
  const float* db2   = (const float*)d_in[27];
  (void)in_sizes; (void)n_in; (void)out_size;

  // ---- workspace layout (bytes, 256-aligned) ----
  char* base = (char*)d_ws;
  size_t off = 0;
  auto alloc = [&](size_t bytes) -> char* {
    char* p = base + off;
    off = (off + bytes + 255) & ~(size_t)255;
    return p;
  };
  unsigned short* seqb  = (unsigned short*)alloc(51200UL*256*2);   // 26.2 MB
  unsigned short* gxb   = (unsigned short*)alloc(51200UL*800*2);   // 81.9 MB
  unsigned short* hb    = (unsigned short*)alloc(51200UL*224*2);   // 22.9 MB
  float*          sqb   = (float*)alloc(51200UL*200*4);            // 41.0 MB
  float*          ekb   = (float*)alloc(51200UL*200*4);            // 41.0 MB
  float*          vb    = (float*)alloc(51200UL*200*4);            // 41.0 MB
  unsigned short* wihp  = (unsigned short*)alloc(204800UL*2);
  float*          bihp  = (float*)alloc(800UL*4);
  unsigned short* wqkvp = (unsigned short*)alloc(150528UL*2);
  float*          bqkvp = (float*)alloc(672UL*4);
  unsigned short* whhpk = (unsigned short*)alloc(114688UL*2);
  unsigned short* dw1p  = (unsigned short*)alloc(1310720UL*2);     // 2.6 MB
  unsigned short* cwp   = (unsigned short*)alloc(98304UL*2);
  float*          cwb   = (float*)alloc(192UL*4);
  if (off > ws_size) return;                 // ~258 MB total
  unsigned short* attb = (unsigned short*)gxb; // overlay: gx dead after scan
  float* part = (float*)seqb;                  // overlay: seq dead after gx GEMM

  hipFuncSetAttribute(reinterpret_cast<const void*>(k_attn),
                      hipFuncAttributeMaxDynamicSharedMemorySize, 51200);
  hipFuncSetAttribute(reinterpret_cast<const void*>(k_embconv2),
                      hipFuncAttributeMaxDynamicSharedMemorySize, 71424);

  k_pack<<<dim3(7347), 256, 0, stream>>>(wih_f, bih_f, bhh_f, wih_b, bih_b, bhh_b,
                                         whh_f, whh_b, wq, bq, wk, bk, wv, bv, dw1,
                                         cw2, cb2, cw3, cb3, cw8, cb8,
                                         wihp, bihp, wqkvp, bqkvp, whhpk, dw1p, cwp, cwb);
  k_embconv2<<<dim3(512), 256, 71424, stream>>>(x, emb1, emb2, cwp, cwb, seqb);
  // gx = seq @ [wih_f|wih_b]^T + biases  -> bf16 (M=51200, N=800, K=256)
  k_gemm_mfma<5, 8, 0, 1><<<dim3(400, 10), 256, 0, stream>>>(seqb, wihp, bihp, gxb, 800, 800);
  k_scan<<<dim3(256, 2), 256, 0, stream>>>(gxb, whhpk, hb);
  // q/k/v GEMMs (M=51200, N=200 pad 224, K=224), epilogue sigmoid/exp/none
  k_gemm_mfma<7, 7, 1, 0><<<dim3(400, 2), 256, 0, stream>>>(hb, wqkvp,          bqkvp,       sqb, 200, 200);
  k_gemm_mfma<7, 7, 2, 0><<<dim3(400, 2), 256, 0, stream>>>(hb, wqkvp + 50176,  bqkvp + 224, ekb, 200, 200);
  k_gemm_mfma<7, 7, 0, 0><<<dim3(400, 2), 256, 0, stream>>>(hb, wqkvp + 100352, bqkvp + 448, vb,  200, 200);
  k_attn<<<dim3(1024), 256, 51200, stream>>>(sqb, ekb, vb, pos_bias, attb);
  k_dense1m<<<dim3(8, NSPL_), 256, 0, stream>>>(attb, dw1p, part);
  k_dense2<<<dim3(1024), 128, 0, stream>>>(part, db1, dw2, db2, (float*)d_out);
}